// Round 6
// baseline (395.032 us; speedup 1.0000x reference)
//
#include <hip/hip_runtime.h>
#include <stdint.h>

typedef unsigned short u16;
typedef __bf16 bf16x8 __attribute__((ext_vector_type(8), may_alias));
typedef float f32x4 __attribute__((ext_vector_type(4), may_alias));

typedef void __attribute__((address_space(1))) as1_void;
typedef void __attribute__((address_space(3))) as3_void;

#define MFMA16 __builtin_amdgcn_mfma_f32_16x16x32_bf16

#define SBAR()                                \
    do {                                      \
        asm volatile("" ::: "memory");        \
        __builtin_amdgcn_s_barrier();         \
        asm volatile("" ::: "memory");        \
    } while (0)
#define WAITV(n) asm volatile("s_waitcnt vmcnt(" #n ")" ::: "memory")
#define WAITL(n) asm volatile("s_waitcnt lgkmcnt(" #n ")" ::: "memory")

__device__ __forceinline__ void async_copy16(const void* g, void* l) {
    __builtin_amdgcn_global_load_lds((as1_void*)g, (as3_void*)l, 16, 0, 0);
}

// round-to-nearest-even fp32 -> bf16 bits
__device__ __forceinline__ u16 f2bf(float f) {
    union { float f; unsigned u; } c; c.f = f;
    unsigned u = c.u;
    u += 0x7fffu + ((u >> 16) & 1u);
    return (u16)(u >> 16);
}

// ---------------- elementwise cast fp32 -> bf16 (vectorized x4, optional scale) --
__global__ __launch_bounds__(256) void cast_f32_bf16(
    const float* __restrict__ in, u16* __restrict__ out, int n4, float scale) {
    int i = blockIdx.x * 256 + threadIdx.x;
    if (i < n4) {
        f32x4 v = *(const f32x4*)&in[(size_t)i * 4];
        ushort4 o;
        o.x = f2bf(v[0] * scale); o.y = f2bf(v[1] * scale);
        o.z = f2bf(v[2] * scale); o.w = f2bf(v[3] * scale);
        *(ushort4*)&out[(size_t)i * 4] = o;
    }
}

// ---------------- tiled transpose + cast: in fp32 (R,C) -> out bf16 (C,R) -----
__global__ __launch_bounds__(256) void transpose_cast(
    const float* __restrict__ in, u16* __restrict__ out, int R, int C) {
    __shared__ float tile[64][65];
    const float* inb = in + (size_t)blockIdx.z * R * C;
    u16* outb = out + (size_t)blockIdx.z * R * C;
    int t = threadIdx.x;
    int c0 = blockIdx.x * 64, r0 = blockIdx.y * 64;
    int tr = t >> 4, tc = (t & 15) * 4;
#pragma unroll
    for (int p = 0; p < 4; ++p) {
        int r = tr + p * 16;
        f32x4 v = *(const f32x4*)&inb[(size_t)(r0 + r) * C + c0 + tc];
        tile[r][tc] = v[0]; tile[r][tc + 1] = v[1];
        tile[r][tc + 2] = v[2]; tile[r][tc + 3] = v[3];
    }
    __syncthreads();
    int wc = t >> 4, wr = (t & 15) * 4;
#pragma unroll
    for (int p = 0; p < 4; ++p) {
        int cl = wc + p * 16;
        ushort4 o;
        o.x = f2bf(tile[wr + 0][cl]); o.y = f2bf(tile[wr + 1][cl]);
        o.z = f2bf(tile[wr + 2][cl]); o.w = f2bf(tile[wr + 3][cl]);
        *(ushort4*)&outb[(size_t)(c0 + cl) * R + r0 + wr] = o;
    }
}

// ---------------- flash attention v3 (transposed dataflow, 2 q-tiles/wave) -----
__global__ __launch_bounds__(256) void flash_attn(
    const u16* __restrict__ Q, const u16* __restrict__ Kb,
    const u16* __restrict__ VT, const int* __restrict__ mask,
    u16* __restrict__ O) {
    __shared__ u16 kls[2][8192];   // K tile 128x64, fragment order, double-buffered
    __shared__ u16 vls[8192];      // V^T tile 64x128, fragment order
    __shared__ u16 pls[8][2048];   // per-wave x per-qtile P^T 16x128, XOR-swizzled

    const int bid = blockIdx.x;
    const int qt = bid & 15;
    const int h = (bid >> 4) & 15;
    const int n = bid >> 8;
    const int t = threadIdx.x;
    const int w = t >> 6, lane = t & 63;
    const int m16 = lane & 15, quad = lane >> 4;

    const size_t qrowA = (size_t)(n * 2048 + qt * 128 + w * 16 + m16);
    const size_t qrowB = qrowA + 64;
    bf16x8 qfA0 = *(const bf16x8*)&Q[qrowA * 1024 + h * 64 + quad * 8];
    bf16x8 qfA1 = *(const bf16x8*)&Q[qrowA * 1024 + h * 64 + 32 + quad * 8];
    bf16x8 qfB0 = *(const bf16x8*)&Q[qrowB * 1024 + h * 64 + quad * 8];
    bf16x8 qfB1 = *(const bf16x8*)&Q[qrowB * 1024 + h * 64 + 32 + quad * 8];

    const int* maskn = mask + n * 2048;
    int allones;
    {
        int ok = 1;
#pragma unroll
        for (int i = 0; i < 8; ++i) {
            int4 mv = *(const int4*)&maskn[lane * 32 + i * 4];
            ok &= (mv.x != 0) & (mv.y != 0) & (mv.z != 0) & (mv.w != 0);
        }
        allones = __all(ok);
    }

    f32x4 otA[4] = {}, otB[4] = {};
    f32x4 sumA = {}, sumB = {};

    const u16* Kbase = Kb + (size_t)(n * 2048) * 1024 + h * 64;
    const u16* Vbase = VT + (size_t)(n * 1024 + h * 64) * 2048;
    u16* pwA = &pls[w * 2][0];
    u16* pwB = &pls[w * 2 + 1][0];

#pragma unroll
    for (int i = 0; i < 4; ++i) {
        int e = w * 4 + i;
        async_copy16(&Kbase[(size_t)((e >> 1) * 16 + m16) * 1024 + (e & 1) * 32 + quad * 8],
                     &kls[0][e * 512]);
    }
    __syncthreads();

    for (int kt = 0; kt < 16; ++kt) {
        const u16* kcur = kls[kt & 1];
        if (kt + 1 < 16) {
            u16* knext = kls[(kt + 1) & 1];
#pragma unroll
            for (int i = 0; i < 4; ++i) {
                int e = w * 4 + i;
                async_copy16(&Kbase[(size_t)((kt + 1) * 128 + (e >> 1) * 16 + m16) * 1024 +
                                    (e & 1) * 32 + quad * 8], &knext[e * 512]);
            }
        }
#pragma unroll
        for (int i = 0; i < 4; ++i) {
            int e = w * 4 + i;
            async_copy16(&Vbase[(size_t)((e >> 2) * 16 + m16) * 2048 + kt * 128 +
                                (e & 3) * 32 + quad * 8], &vls[e * 512]);
        }

        f32x4 sA[8] = {}, sB[8] = {};
#pragma unroll
        for (int ct = 0; ct < 8; ++ct) {
            bf16x8 a0 = *(const bf16x8*)&kcur[(ct * 2 + 0) * 512 + lane * 8];
            bf16x8 a1 = *(const bf16x8*)&kcur[(ct * 2 + 1) * 512 + lane * 8];
            sA[ct] = MFMA16(a0, qfA0, sA[ct], 0, 0, 0);
            sA[ct] = MFMA16(a1, qfA1, sA[ct], 0, 0, 0);
            sB[ct] = MFMA16(a0, qfB0, sB[ct], 0, 0, 0);
            sB[ct] = MFMA16(a1, qfB1, sB[ct], 0, 0, 0);
        }

        if (allones) {
#pragma unroll
            for (int ct = 0; ct < 8; ++ct) {
                int c = ct * 2 + (quad >> 1);
                int off = m16 * 128 + (((c ^ m16) & 15) << 3) + (quad & 1) * 4;
                {
                    float p0 = __builtin_amdgcn_exp2f(sA[ct][0]);
                    float p1 = __builtin_amdgcn_exp2f(sA[ct][1]);
                    float p2 = __builtin_amdgcn_exp2f(sA[ct][2]);
                    float p3 = __builtin_amdgcn_exp2f(sA[ct][3]);
                    sumA[0] += p0; sumA[1] += p1; sumA[2] += p2; sumA[3] += p3;
                    unsigned lo = __builtin_amdgcn_perm(__float_as_uint(p1), __float_as_uint(p0), 0x07060302);
                    unsigned hi = __builtin_amdgcn_perm(__float_as_uint(p3), __float_as_uint(p2), 0x07060302);
                    *(uint2*)&pwA[off] = make_uint2(lo, hi);
                }
                {
                    float p0 = __builtin_amdgcn_exp2f(sB[ct][0]);
                    float p1 = __builtin_amdgcn_exp2f(sB[ct][1]);
                    float p2 = __builtin_amdgcn_exp2f(sB[ct][2]);
                    float p3 = __builtin_amdgcn_exp2f(sB[ct][3]);
                    sumB[0] += p0; sumB[1] += p1; sumB[2] += p2; sumB[3] += p3;
                    unsigned lo = __builtin_amdgcn_perm(__float_as_uint(p1), __float_as_uint(p0), 0x07060302);
                    unsigned hi = __builtin_amdgcn_perm(__float_as_uint(p3), __float_as_uint(p2), 0x07060302);
                    *(uint2*)&pwB[off] = make_uint2(lo, hi);
                }
            }
        } else {
#pragma unroll
            for (int ct = 0; ct < 8; ++ct) {
                const int4 mv = *(const int4*)&maskn[kt * 128 + ct * 16 + quad * 4];
                int c = ct * 2 + (quad >> 1);
                int off = m16 * 128 + (((c ^ m16) & 15) << 3) + (quad & 1) * 4;
                {
                    float p0 = __builtin_amdgcn_exp2f(sA[ct][0]) * (mv.x ? 1.f : 0.f);
                    float p1 = __builtin_amdgcn_exp2f(sA[ct][1]) * (mv.y ? 1.f : 0.f);
                    float p2 = __builtin_amdgcn_exp2f(sA[ct][2]) * (mv.z ? 1.f : 0.f);
                    float p3 = __builtin_amdgcn_exp2f(sA[ct][3]) * (mv.w ? 1.f : 0.f);
                    sumA[0] += p0; sumA[1] += p1; sumA[2] += p2; sumA[3] += p3;
                    unsigned lo = __builtin_amdgcn_perm(__float_as_uint(p1), __float_as_uint(p0), 0x07060302);
                    unsigned hi = __builtin_amdgcn_perm(__float_as_uint(p3), __float_as_uint(p2), 0x07060302);
                    *(uint2*)&pwA[off] = make_uint2(lo, hi);
                }
                {
                    float p0 = __builtin_amdgcn_exp2f(sB[ct][0]) * (mv.x ? 1.f : 0.f);
                    float p1 = __builtin_amdgcn_exp2f(sB[ct][1]) * (mv.y ? 1.f : 0.f);
                    float p2 = __builtin_amdgcn_exp2f(sB[ct][2]) * (mv.z ? 1.f : 0.f);
                    float p3 = __builtin_amdgcn_exp2f(sB[ct][3]) * (mv.w ? 1.f : 0.f);
                    sumB[0] += p0; sumB[1] += p1; sumB[2] += p2; sumB[3] += p3;
                    unsigned lo = __builtin_amdgcn_perm(__float_as_uint(p1), __float_as_uint(p0), 0x07060302);
                    unsigned hi = __builtin_amdgcn_perm(__float_as_uint(p3), __float_as_uint(p2), 0x07060302);
                    *(uint2*)&pwB[off] = make_uint2(lo, hi);
                }
            }
        }

        __syncthreads();

        bf16x8 pfA[4], pfB[4];
#pragma unroll
        for (int kc2 = 0; kc2 < 4; ++kc2) {
            int off = m16 * 128 + ((((kc2 * 4 + quad) ^ m16) & 15) << 3);
            pfA[kc2] = *(const bf16x8*)&pwA[off];
            pfB[kc2] = *(const bf16x8*)&pwB[off];
        }
#pragma unroll
        for (int kc2 = 0; kc2 < 4; ++kc2) {
#pragma unroll
            for (int dt = 0; dt < 4; ++dt) {
                bf16x8 vf = *(const bf16x8*)&vls[(dt * 4 + kc2) * 512 + lane * 8];
                otA[dt] = MFMA16(vf, pfA[kc2], otA[dt], 0, 0, 0);
                otB[dt] = MFMA16(vf, pfB[kc2], otB[dt], 0, 0, 0);
            }
        }
        __syncthreads();
    }

    float lA = (sumA[0] + sumA[1]) + (sumA[2] + sumA[3]);
    float lB = (sumB[0] + sumB[1]) + (sumB[2] + sumB[3]);
    lA += __shfl_xor(lA, 16); lA += __shfl_xor(lA, 32);
    lB += __shfl_xor(lB, 16); lB += __shfl_xor(lB, 32);
    float invA = 1.f / fmaxf(lA, 1e-30f);
    float invB = 1.f / fmaxf(lB, 1e-30f);

    const size_t obA = qrowA * 1024 + h * 64;
    const size_t obB = qrowB * 1024 + h * 64;
#pragma unroll
    for (int dt = 0; dt < 4; ++dt) {
        unsigned lo = (unsigned)f2bf(otA[dt][0] * invA) | ((unsigned)f2bf(otA[dt][1] * invA) << 16);
        unsigned hi = (unsigned)f2bf(otA[dt][2] * invA) | ((unsigned)f2bf(otA[dt][3] * invA) << 16);
        *(uint2*)&O[obA + dt * 16 + quad * 4] = make_uint2(lo, hi);
        lo = (unsigned)f2bf(otB[dt][0] * invB) | ((unsigned)f2bf(otB[dt][1] * invB) << 16);
        hi = (unsigned)f2bf(otB[dt][2] * invB) | ((unsigned)f2bf(otB[dt][3] * invB) << 16);
        *(uint2*)&O[obB + dt * 16 + quad * 4] = make_uint2(lo, hi);
    }
}

// ---------------- bf16 GEMM 128-tile (2-phase, small-ws fallback only) --------
template <int BM, int BN, int RELU, int OUTBF, int SPLITK>
__global__ __launch_bounds__(256) void gemm_bt(
    const u16* __restrict__ A, const u16* __restrict__ Bt,
    const float* __restrict__ bias, void* __restrict__ Cout,
    void* __restrict__ Cout1, int M, int N, int K) {
    constexpr int MI = BM / 32;
    constexpr int NJ = BN / 32;
    __shared__ u16 sm[2][(BM + BN) * 64];
    const int lane = threadIdx.x & 63;
    const int w = threadIdx.x >> 6;
    const int m16 = lane & 15, quad = lane >> 4;
    const int nBn = N / BN;
    int bid = blockIdx.x;
    int slice = 0;
    if (SPLITK > 1) {
        const int nblk = (M / BM) * nBn;
        slice = bid / nblk;
        bid = bid - slice * nblk;
    }
    const int bm = bid / nBn, bn = bid % nBn;
    const int r2 = w >> 1, c2 = w & 1;
    const int Ks = K / SPLITK;
    const int kOff = slice * Ks;

    const u16* Abase = A + (size_t)(bm * BM + m16) * K + quad * 8;
    const u16* Bbase = Bt + (size_t)(bn * BN + m16) * K + quad * 8;

    auto stage = [&](int buf, int k0) {
        u16* smA = &sm[buf][0];
        u16* smB = smA + BM * 64;
#pragma unroll
        for (int i = 0; i < MI; ++i) {
            int e = w * MI + i;
            async_copy16(&Abase[(size_t)((e >> 1) * 16) * K + k0 + (e & 1) * 32], &smA[e * 512]);
        }
#pragma unroll
        for (int i = 0; i < NJ; ++i) {
            int e = w * NJ + i;
            async_copy16(&Bbase[(size_t)((e >> 1) * 16) * K + k0 + (e & 1) * 32], &smB[e * 512]);
        }
    };

    f32x4 acc[MI][NJ] = {};
    const int nK = Ks >> 6;
    stage(0, kOff);
    __syncthreads();
    for (int kt = 0; kt < nK; ++kt) {
        if (kt + 1 < nK) stage((kt + 1) & 1, kOff + ((kt + 1) << 6));
        const u16* smA = &sm[kt & 1][0];
        const u16* smB = smA + BM * 64;
#pragma unroll
        for (int kc = 0; kc < 2; ++kc) {
            bf16x8 a[MI], b[NJ];
#pragma unroll
            for (int i = 0; i < MI; ++i)
                a[i] = *(const bf16x8*)&smA[((r2 * MI + i) * 2 + kc) * 512 + lane * 8];
#pragma unroll
            for (int j = 0; j < NJ; ++j)
                b[j] = *(const bf16x8*)&smB[((c2 * NJ + j) * 2 + kc) * 512 + lane * 8];
#pragma unroll
            for (int i = 0; i < MI; ++i)
#pragma unroll
                for (int j = 0; j < NJ; ++j)
                    acc[i][j] = MFMA16(a[i], b[j], acc[i][j], 0, 0, 0);
        }
        __syncthreads();
    }
    float bv[NJ];
#pragma unroll
    for (int j = 0; j < NJ; ++j)
        bv[j] = (SPLITK == 1 || slice == 0)
                    ? bias[bn * BN + c2 * (BN / 2) + j * 16 + m16] : 0.f;
    void* Csel = (SPLITK > 1 && slice != 0) ? Cout1 : Cout;
#pragma unroll
    for (int i = 0; i < MI; ++i) {
        int row0 = bm * BM + r2 * (BM / 2) + i * 16 + quad * 4;
#pragma unroll
        for (int j = 0; j < NJ; ++j) {
            int col = bn * BN + c2 * (BN / 2) + j * 16 + m16;
#pragma unroll
            for (int r = 0; r < 4; ++r) {
                float v = acc[i][j][r] + bv[j];
                if (RELU) v = fmaxf(v, 0.f);
                size_t idx = (size_t)(row0 + r) * N + col;
                if (OUTBF) ((u16*)Csel)[idx] = f2bf(v);
                else ((float*)Csel)[idx] = v;
            }
        }
    }
}

// ---------------- 256x256 8-phase GEMM (read-ahead, counted lgkm) -------------
// Each phase issues the ds_reads for a LATER quadrant, then waits only for
// older reads (counted lgkmcnt); reads drain under the current MFMA cluster.
// Quadrants: Q1=(a0,b01) Q2=(a0,b23) Q3=(a1,b23) Q4=(a1,b01).
// b01 is REGISTER-DOUBLE-BUFFERED (b01E/b01O): Q4(E) at ph4 consumes b01E
// while ph4's read-ahead fills b01O (round-5 bug: single b01 was overwritten
// before Q4's use). a0/a1/b23 lifetimes verified safe as single sets.
// lgkm ledger (steady state): ph1 W(4) drains a0+b01E; ph2 W(8) drains b23;
// ph3 W(0) drains a1; ph4/ph8 W(12) no-op (operands already drained).
// Stage units: p0=A-even(a0) p1=A-odd(a1) p2=B-lo p3=B-hi; gates WAITV(6)
// at ph4/ph8 drain the full next buffer (verified ledger in session notes).
template <int RELU, int OUTBF>
__global__ __launch_bounds__(512, 2) void gemm_8ph(
    const u16* __restrict__ A, const u16* __restrict__ Bt,
    const float* __restrict__ bias, void* __restrict__ Cout,
    int M, int N, int K) {
    __shared__ u16 sm[2][2][16384];   // [buf][A=0/B=1][256x64 fragment order]
    const int t = threadIdx.x;
    const int w = t >> 6, lane = t & 63;
    const int m16 = lane & 15, quad = lane >> 4;
    const int wm = w >> 2, wn = w & 3;
    const int nBn = N >> 8;
    const int bid = blockIdx.x;
    const int bm = bid / nBn, bn = bid % nBn;
    const int nK = K >> 6, nIter = nK >> 1;
    const u16* Abase = A + (size_t)(bm * 256 + m16) * K + quad * 8;
    const u16* Bbase = Bt + (size_t)(bn * 256 + m16) * K + quad * 8;

    auto stage_ht = [&](int kt, int part) {
        if (kt < nK) {
            const u16* base = (part < 2) ? Abase : Bbase;
            u16* lds = &sm[kt & 1][part >> 1][0];
#pragma unroll
            for (int i = 0; i < 2; ++i) {
                int e;
                if (part == 0)      e = i * 16 + w;       // A-even (a0 regions)
                else if (part == 1) e = 8 + i * 16 + w;   // A-odd  (a1 regions)
                else if (part == 2) e = i * 8 + w;        // B-lo
                else                e = 16 + i * 8 + w;   // B-hi
                async_copy16(&base[(size_t)((e >> 1) * 16) * K + (size_t)kt * 64 + (e & 1) * 32],
                             &lds[e * 512]);
            }
        }
    };
    auto ldsA = [&](int buf, int mf, int kc) {
        return *(const bf16x8*)&sm[buf][0][((wm * 8 + mf) * 2 + kc) * 512 + lane * 8];
    };
    auto ldsB = [&](int buf, int nf, int kc) {
        return *(const bf16x8*)&sm[buf][1][((wn * 4 + nf) * 2 + kc) * 512 + lane * 8];
    };

    f32x4 acc[8][4] = {};
    bf16x8 a0[4][2], a1[4][2], b01E[2][2], b01O[2][2], b23[2][2];

#define RD_A0(buf)                                                              \
    _Pragma("unroll") for (int mf = 0; mf < 4; ++mf) {                          \
        a0[mf][0] = ldsA(buf, mf, 0); a0[mf][1] = ldsA(buf, mf, 1); }
#define RD_A1(buf)                                                              \
    _Pragma("unroll") for (int mf = 0; mf < 4; ++mf) {                          \
        a1[mf][0] = ldsA(buf, mf + 4, 0); a1[mf][1] = ldsA(buf, mf + 4, 1); }
#define RD_B01E(buf)                                                            \
    _Pragma("unroll") for (int nf = 0; nf < 2; ++nf) {                          \
        b01E[nf][0] = ldsB(buf, nf, 0); b01E[nf][1] = ldsB(buf, nf, 1); }
#define RD_B01O(buf)                                                            \
    _Pragma("unroll") for (int nf = 0; nf < 2; ++nf) {                          \
        b01O[nf][0] = ldsB(buf, nf, 0); b01O[nf][1] = ldsB(buf, nf, 1); }
#define RD_B23(buf)                                                             \
    _Pragma("unroll") for (int nf = 0; nf < 2; ++nf) {                          \
        b23[nf][0] = ldsB(buf, 2 + nf, 0); b23[nf][1] = ldsB(buf, 2 + nf, 1); }
#define QUAD8(Ar, Br, MO, NO)                                                   \
    do {                                                                        \
        __builtin_amdgcn_s_setprio(1);                                          \
        _Pragma("unroll") for (int mi = 0; mi < 4; ++mi)                        \
            _Pragma("unroll") for (int nj = 0; nj < 2; ++nj)                    \
                _Pragma("unroll") for (int kc = 0; kc < 2; ++kc)                \
                    acc[(MO) + mi][(NO) + nj] =                                 \
                        MFMA16(Ar[mi][kc], Br[nj][kc],                          \
                               acc[(MO) + mi][(NO) + nj], 0, 0, 0);             \
        __builtin_amdgcn_s_setprio(0);                                          \
    } while (0)

    // prologue: tile0 fully + tile1 {p0,p1,p2} in flight; then Q1 operand reads
    stage_ht(0, 0); stage_ht(0, 1); stage_ht(0, 2); stage_ht(0, 3);
    stage_ht(1, 0); stage_ht(1, 1); stage_ht(1, 2);
    WAITV(6);
    SBAR();
    RD_A0(0); RD_B01E(0);

    for (int it = 0; it < nIter; ++it) {
        const int T1 = 2 * it + 1, T2 = 2 * it + 2, T3 = 2 * it + 3;
        const bool last = (it + 1 == nIter);
        // ph1: read b23E (for Q2); stage T1,B-hi; MFMA Q1(E)
        RD_B23(0); stage_ht(T1, 3);
        SBAR(); WAITL(4);
        QUAD8(a0, b01E, 0, 0);
        SBAR();
        // ph2: read a1E (for Q3); stage T2,A-even; MFMA Q2(E)
        RD_A1(0); stage_ht(T2, 0);
        SBAR(); WAITL(8);
        QUAD8(a0, b23, 0, 2);
        SBAR();
        // ph3: MFMA Q3(E)  (no reads/stages; single barrier)
        WAITL(0);
        QUAD8(a1, b23, 4, 2);
        SBAR();
        // ph4: stage T2 A-odd + B-lo; gate bufO(T1); read a0O,b01O; MFMA Q4(E)=b01E
        stage_ht(T2, 1); stage_ht(T2, 2);
        if (last) { WAITV(0); } else { WAITV(6); }
        SBAR();
        RD_A0(1); RD_B01O(1);
        WAITL(12);
        QUAD8(a1, b01E, 4, 0);
        SBAR();
        // ph5: read b23O; stage T2,B-hi; MFMA Q1(O)
        RD_B23(1); stage_ht(T2, 3);
        SBAR(); WAITL(4);
        QUAD8(a0, b01O, 0, 0);
        SBAR();
        // ph6: read a1O; stage T3,A-even; MFMA Q2(O)
        RD_A1(1); stage_ht(T3, 0);
        SBAR(); WAITL(8);
        QUAD8(a0, b23, 0, 2);
        SBAR();
        // ph7: MFMA Q3(O)
        WAITL(0);
        QUAD8(a1, b23, 4, 2);
        SBAR();
        // ph8: stage T3 A-odd + B-lo; gate bufE(T2); read a0E',b01E'; MFMA Q4(O)=b01O
        stage_ht(T3, 1); stage_ht(T3, 2);
        if (last) { WAITV(0); } else { WAITV(6); }
        SBAR();
        if (!last) { RD_A0(0); RD_B01E(0); }
        WAITL(12);
        QUAD8(a1, b01O, 4, 0);
        SBAR();
    }
#undef QUAD8
#undef RD_A0
#undef RD_A1
#undef RD_B01E
#undef RD_B01O
#undef RD_B23

    float bv[4];
#pragma unroll
    for (int nf = 0; nf < 4; ++nf)
        bv[nf] = bias[bn * 256 + wn * 64 + nf * 16 + m16];
    const int colb = bn * 256 + wn * 64 + m16;
#pragma unroll
    for (int mf = 0; mf < 8; ++mf) {
        const int row0 = bm * 256 + wm * 128 + mf * 16 + quad * 4;
#pragma unroll
        for (int nf = 0; nf < 4; ++nf) {
#pragma unroll
            for (int r = 0; r < 4; ++r) {
                float vv = acc[mf][nf][r] + bv[nf];
                if (RELU) vv = fmaxf(vv, 0.f);
                size_t idx = (size_t)(row0 + r) * N + colb + nf * 16;
                if (OUTBF) ((u16*)Cout)[idx] = f2bf(vv);
                else ((float*)Cout)[idx] = vv;
            }
        }
    }
}

// ---------------- 128x256 split-K 4-phase GEMM (read-ahead, counted lgkm) -----
// Quadrants per K-tile: Q1=(af,alpha) Q2=(af,beta). af register-double-buffered
// (afE/afO); al/be single sets — verified: each is fully consumed before its
// overwrite phase (al used ph1/ph3, overwritten ph2/ph4; be used ph2/ph4,
// overwritten ph3/next-ph1). Stages: ph1:T1p2 ph2:T2p0,T2p1+gate(4)
// ph3:T2p2 ph4:T3p0,T3p1+gate(4).
template <int RELU, int OUTBF, int SPLITK>
__global__ __launch_bounds__(512, 2) void gemm_sk(
    const u16* __restrict__ A, const u16* __restrict__ Bt,
    const float* __restrict__ bias,
    void* __restrict__ C0, void* __restrict__ C1,
    int M, int N, int K) {
    __shared__ u16 smA[2][8192];    // 128x64 per buf
    __shared__ u16 smB[2][16384];   // 256x64 per buf
    const int t = threadIdx.x;
    const int w = t >> 6, lane = t & 63;
    const int m16 = lane & 15, quad = lane >> 4;
    const int wm = w >> 2, wn = w & 3;                 // 2 x 4 wave grid
    const int nBn = N >> 8;
    const int nblk = (M >> 7) * nBn * SPLITK;
    const int o = blockIdx.x;
    const int v = (o & 7) * (nblk >> 3) + (o >> 3);    // XCD-chunked (nblk%8==0)
    const int gsz = nBn * SPLITK;
    const int bm = v / gsz;
    const int rr = v - bm * gsz;
    const int slice = rr / nBn;
    const int bn = rr - slice * nBn;
    const int Ks = K / SPLITK;
    const int nK = Ks >> 6, nIter = nK >> 1;
    const u16* Abase = A + (size_t)(bm * 128 + m16) * K + slice * Ks + quad * 8;
    const u16* Bbase = Bt + (size_t)(bn * 256 + m16) * K + slice * Ks + quad * 8;

    // unit (kt, part): part 0 = A (16 KB), 1 = B-alpha, 2 = B-beta
    auto stage_u = [&](int kt, int part) {
        if (kt < nK) {
#pragma unroll
            for (int i = 0; i < 2; ++i) {
                const int idx = i * 8 + w;
                int e;
                const u16* base;
                u16* lds;
                if (part == 0) {
                    e = idx; base = Abase; lds = &smA[kt & 1][0];
                } else {
                    const int rbs = idx >> 1;
                    const int rb = ((rbs >> 1) << 2) | (rbs & 1) | ((part == 2) ? 2 : 0);
                    e = rb * 2 + (idx & 1);
                    base = Bbase; lds = &smB[kt & 1][0];
                }
                async_copy16(&base[(size_t)((e >> 1) * 16) * K + (size_t)kt * 64 + (e & 1) * 32],
                             &lds[e * 512]);
            }
        }
    };
    auto ldsA = [&](int buf, int mf, int kc) {
        return *(const bf16x8*)&smA[buf][((wm * 4 + mf) * 2 + kc) * 512 + lane * 8];
    };
    auto ldsB = [&](int buf, int nf, int kc) {
        return *(const bf16x8*)&smB[buf][((wn * 4 + nf) * 2 + kc) * 512 + lane * 8];
    };

    f32x4 acc[4][4] = {};
    bf16x8 afE[4][2], afO[4][2], al[2][2], be[2][2];

#define RD_AFE(buf)                                                             \
    _Pragma("unroll") for (int mf = 0; mf < 4; ++mf) {                          \
        afE[mf][0] = ldsA(buf, mf, 0); afE[mf][1] = ldsA(buf, mf, 1); }
#define RD_AFO(buf)                                                             \
    _Pragma("unroll") for (int mf = 0; mf < 4; ++mf) {                          \
        afO[mf][0] = ldsA(buf, mf, 0); afO[mf][1] = ldsA(buf, mf, 1); }
#define RD_AL(buf)                                                              \
    _Pragma("unroll") for (int nf = 0; nf < 2; ++nf) {                          \
        al[nf][0] = ldsB(buf, nf, 0); al[nf][1] = ldsB(buf, nf, 1); }
#define RD_BE(buf)                                                              \
    _Pragma("unroll") for (int nf = 0; nf < 2; ++nf) {                          \
        be[nf][0] = ldsB(buf, 2 + nf, 0); be[nf][1] = ldsB(buf, 2 + nf, 1); }
#define QUADS(Ar, Br, NO)                                                       \
    do {                                                                        \
        __builtin_amdgcn_s_setprio(1);                                          \
        _Pragma("unroll") for (int mi = 0; mi < 4; ++mi)                        \
            _Pragma("unroll") for (int nj = 0; nj < 2; ++nj)                    \
                _Pragma("unroll") for (int kc = 0; kc < 2; ++kc)                \
                    acc[mi][(NO) + nj] =                                        \
                        MFMA16(Ar[mi][kc], Br[nj][kc],                          \
                               acc[mi][(NO) + nj], 0, 0, 0);                    \
        __builtin_amdgcn_s_setprio(0);                                          \
    } while (0)

    // prologue: tile0 fully + tile1 A/alpha in flight; then Q1 operand reads
    stage_u(0, 0); stage_u(0, 1); stage_u(0, 2);
    stage_u(1, 0); stage_u(1, 1);
    WAITV(4);
    SBAR();
    RD_AFE(0); RD_AL(0);

    for (int it = 0; it < nIter; ++it) {
        const int T1 = 2 * it + 1, T2 = 2 * it + 2, T3 = 2 * it + 3;
        const bool last = (it + 1 == nIter);
        // ph1: read betaE (for Q2); stage T1,beta; MFMA Q1(E)
        RD_BE(0); stage_u(T1, 2);
        SBAR(); WAITL(4);
        QUADS(afE, al, 0);
        SBAR();
        // ph2: stage T2 A+alpha; gate bufO(T1); read afO,alphaO; MFMA Q2(E)
        stage_u(T2, 0); stage_u(T2, 1);
        if (last) { WAITV(0); } else { WAITV(4); }
        SBAR();
        RD_AFO(1); RD_AL(1);
        WAITL(12);
        QUADS(afE, be, 2);
        SBAR();
        // ph3: read betaO; stage T2,beta; MFMA Q1(O)
        RD_BE(1); stage_u(T2, 2);
        SBAR(); WAITL(4);
        QUADS(afO, al, 0);
        SBAR();
        // ph4: stage T3 A+alpha; gate bufE(T2); read afE',alphaE'; MFMA Q2(O)
        stage_u(T3, 0); stage_u(T3, 1);
        if (last) { WAITV(0); } else { WAITV(4); }
        SBAR();
        if (!last) { RD_AFE(0); RD_AL(0); }
        WAITL(12);
        QUADS(afO, be, 2);
        SBAR();
    }
#undef QUADS
#undef RD_AFE
#undef RD_AFO
#undef RD_AL
#undef RD_BE

    float bv[4];
#pragma unroll
    for (int nf = 0; nf < 4; ++nf)
        bv[nf] = (SPLITK == 1 || slice == 0)
                     ? bias[bn * 256 + wn * 64 + nf * 16 + m16] : 0.f;
    void* Csel = (SPLITK > 1 && slice != 0) ? C1 : C0;
    const int colb = bn * 256 + wn * 64 + m16;
#pragma unroll
    for (int mf = 0; mf < 4; ++mf) {
        const int row0 = bm * 128 + wm * 64 + mf * 16 + quad * 4;
#pragma unroll
        for (int nf = 0; nf < 4; ++nf) {
#pragma unroll
            for (int r = 0; r < 4; ++r) {
                float vv = acc[mf][nf][r] + bv[nf];
                if (RELU) vv = fmaxf(vv, 0.f);
                size_t idx = (size_t)(row0 + r) * N + colb + nf * 16;
                if (OUTBF) ((u16*)Csel)[idx] = f2bf(vv);
                else ((float*)Csel)[idx] = vv;
            }
        }
    }
}

// ---------------- residual + layernorm (row = 1024) ----------------
// out = LN(x + x2 + res); x2 optional split-K partial.
__global__ __launch_bounds__(256) void ln_residual(
    const float* __restrict__ x, const float* x2,
    const float* __restrict__ res,
    const float* __restrict__ g, const float* __restrict__ b,
    float* __restrict__ out_f32, u16* __restrict__ out_bf16) {
    __shared__ float smr[8];
    int row = blockIdx.x;
    int t = threadIdx.x;
    f32x4 xv = *(const f32x4*)&x[(size_t)row * 1024 + t * 4];
    f32x4 rv = *(const f32x4*)&res[(size_t)row * 1024 + t * 4];
    xv += rv;
    if (x2) xv += *(const f32x4*)&x2[(size_t)row * 1024 + t * 4];
    float s = xv[0] + xv[1] + xv[2] + xv[3];
    float ss = xv[0] * xv[0] + xv[1] * xv[1] + xv[2] * xv[2] + xv[3] * xv[3];
#pragma unroll
    for (int d = 1; d < 64; d <<= 1) {
        s += __shfl_xor(s, d);
        ss += __shfl_xor(ss, d);
    }
    int w = t >> 6, lane = t & 63;
    if (lane == 0) { smr[w] = s; smr[4 + w] = ss; }
    __syncthreads();
    s = smr[0] + smr[1] + smr[2] + smr[3];
    ss = smr[4] + smr[5] + smr[6] + smr[7];
    float mu = s * (1.f / 1024.f);
    float var = ss * (1.f / 1024.f) - mu * mu;
    float rs = rsqrtf(var + 1e-5f);
    f32x4 gv = *(const f32x4*)&g[t * 4];
    f32x4 bv = *(const f32x4*)&b[t * 4];
    f32x4 y;
#pragma unroll
    for (int i = 0; i < 4; ++i) y[i] = (xv[i] - mu) * rs * gv[i] + bv[i];
    *(f32x4*)&out_f32[(size_t)row * 1024 + t * 4] = y;
    if (out_bf16) {
        ushort4 o;
        o.x = f2bf(y[0]); o.y = f2bf(y[1]); o.z = f2bf(y[2]); o.w = f2bf(y[3]);
        *(ushort4*)&out_bf16[(size_t)row * 1024 + t * 4] = o;
    }
}

extern "C" void kernel_launch(void* const* d_in, const int* in_sizes, int n_in,
                              void* d_out, int out_size, void* d_ws, size_t ws_size,
                              hipStream_t stream) {
    const float* q = (const float*)d_in[0];
    const float* k = (const float*)d_in[1];
    const float* v = (const float*)d_in[2];
    const int* mask = (const int*)d_in[3];
    const float* fc_b = (const float*)d_in[5];
    const float* ln1_g = (const float*)d_in[6];
    const float* ln1_b = (const float*)d_in[7];
    const float* ff_b1 = (const float*)d_in[9];
    const float* ff_b2 = (const float*)d_in[11];
    const float* ln2_g = (const float*)d_in[12];
    const float* ln2_b = (const float*)d_in[13];
    const float* fc_w = (const float*)d_in[4];
    const float* ff_w1 = (const float*)d_in[8];
    const float* ff_w2 = (const float*)d_in[10];

    char* ws = (char*)d_ws;
    const size_t MB = 1024 * 1024;
    u16* qbf = (u16*)(ws + 0);          // 8 MB (pre-scaled)
    u16* kbf = (u16*)(ws + 8 * MB);     // 8 MB
    u16* vT  = (u16*)(ws + 16 * MB);    // 8 MB
    u16* ao  = (u16*)(ws + 24 * MB);    // 8 MB
    u16* hbuf = (u16*)(ws + 0);         // 32 MB (after attention+out-proj)
    u16* fcwT = (u16*)(ws + 32 * MB);   // 2 MB
    u16* w1T  = (u16*)(ws + 34 * MB);   // 8 MB
    u16* w2T  = (u16*)(ws + 42 * MB);   // 8 MB
    float* attn_raw = (float*)(ws + 50 * MB); // 16 MB (out-proj slice 0)
    float* fc_raw   = (float*)(ws + 50 * MB); // FFN2 slice 0 (attn_raw dead)
    float* x1   = (float*)(ws + 66 * MB);     // 16 MB
    u16* x1bf   = (u16*)(ws + 82 * MB);       // 8 MB
    float* attn_rawB = (float*)(ws + 0);      // 16 MB (out-proj slice 1; dead region)
    float* fcB  = (float*)(ws + 90 * MB);     // 16 MB (FFN2 slice 1)
    const bool big = ws_size >= 106 * MB;

    const float k2 = 0.03125f * 1.44269504088896340736f; // 1/sqrt(1024)*log2(e)

    // preprocessing
    cast_f32_bf16<<<4096, 256, 0, stream>>>(q, qbf, 1048576, k2);
    cast_f32_bf16<<<4096, 256, 0, stream>>>(k, kbf, 1048576, 1.0f);
    transpose_cast<<<dim3(16, 32, 2), 256, 0, stream>>>(v, vT, 2048, 1024);
    transpose_cast<<<dim3(16, 16, 1), 256, 0, stream>>>(fc_w, fcwT, 1024, 1024);
    transpose_cast<<<dim3(64, 16, 1), 256, 0, stream>>>(ff_w1, w1T, 1024, 4096);
    transpose_cast<<<dim3(16, 64, 1), 256, 0, stream>>>(ff_w2, w2T, 4096, 1024);

    // attention
    flash_attn<<<512, 256, 0, stream>>>(qbf, kbf, vT, mask, ao);

    // out-proj: 128x256 split-K=2 4-phase read-ahead (grid 256, 8 waves)
    gemm_sk<0, 0, 2><<<256, 512, 0, stream>>>(
        ao, fcwT, fc_b, attn_raw, attn_rawB, 4096, 1024, 1024);
    ln_residual<<<4096, 256, 0, stream>>>(attn_raw, attn_rawB, q, ln1_g, ln1_b, x1, x1bf);

    // FFN1: 256x256 8-phase read-ahead (grid 256)
    gemm_8ph<1, 1><<<256, 512, 0, stream>>>(
        x1bf, w1T, ff_b1, hbuf, 4096, 4096, 1024);

    // FFN2: 128x256 split-K=2 4-phase read-ahead (grid 256)
    if (big) {
        gemm_sk<0, 0, 2><<<256, 512, 0, stream>>>(
            hbuf, w2T, ff_b2, fc_raw, fcB, 4096, 1024, 4096);
        ln_residual<<<4096, 256, 0, stream>>>(fc_raw, fcB, x1, ln2_g, ln2_b,
                                              (float*)d_out, (u16*)nullptr);
    } else {
        gemm_bt<64, 128, 0, 0, 1><<<64 * 8, 256, 0, stream>>>(
            hbuf, w2T, ff_b2, fc_raw, nullptr, 4096, 1024, 4096);
        ln_residual<<<4096, 256, 0, stream>>>(fc_raw, nullptr, x1, ln2_g, ln2_b,
                                              (float*)d_out, (u16*)nullptr);
    }
}

// Round 7
// 350.943 us; speedup vs baseline: 1.1256x; 1.1256x over previous
//
#include <hip/hip_runtime.h>
#include <stdint.h>

typedef unsigned short u16;
typedef __bf16 bf16x8 __attribute__((ext_vector_type(8), may_alias));
typedef float f32x4 __attribute__((ext_vector_type(4), may_alias));

typedef void __attribute__((address_space(1))) as1_void;
typedef void __attribute__((address_space(3))) as3_void;

#define MFMA16 __builtin_amdgcn_mfma_f32_16x16x32_bf16

#define SBAR()                                \
    do {                                      \
        asm volatile("" ::: "memory");        \
        __builtin_amdgcn_s_barrier();         \
        asm volatile("" ::: "memory");        \
    } while (0)
#define WAITV(n) asm volatile("s_waitcnt vmcnt(" #n ")" ::: "memory")
#define WAITL0() asm volatile("s_waitcnt lgkmcnt(0)" ::: "memory")

__device__ __forceinline__ void async_copy16(const void* g, void* l) {
    __builtin_amdgcn_global_load_lds((as1_void*)g, (as3_void*)l, 16, 0, 0);
}

// round-to-nearest-even fp32 -> bf16 bits
__device__ __forceinline__ u16 f2bf(float f) {
    union { float f; unsigned u; } c; c.f = f;
    unsigned u = c.u;
    u += 0x7fffu + ((u >> 16) & 1u);
    return (u16)(u >> 16);
}
__device__ __forceinline__ float bf2f(u16 u) {
    return __uint_as_float((unsigned)u << 16);
}

// ---------------- fused preprocessing: 2 casts + 4 transposes, one launch ----
// grid 11520: [0,1024) v-transpose, [1024,1280) fcw-T, [1280,2304) w1-T,
// [2304,3328) w2-T, [3328,7424) q-cast (scaled), [7424,11520) k-cast.
__global__ __launch_bounds__(256) void prep_all(
    const float* __restrict__ q, u16* __restrict__ qbf, float qscale,
    const float* __restrict__ k, u16* __restrict__ kbf,
    const float* __restrict__ v, u16* __restrict__ vT,
    const float* __restrict__ fcw, u16* __restrict__ fcwT,
    const float* __restrict__ w1, u16* __restrict__ w1T,
    const float* __restrict__ w2, u16* __restrict__ w2T) {
    __shared__ float tile[64][65];
    int g = blockIdx.x;
    int t = threadIdx.x;
    if (g >= 3328) {
        g -= 3328;
        const float* in;
        u16* out;
        float sc;
        if (g < 4096) { in = q; out = qbf; sc = qscale; }
        else { g -= 4096; in = k; out = kbf; sc = 1.0f; }
        size_t i = (size_t)g * 256 + t;
        f32x4 vv = *(const f32x4*)&in[i * 4];
        ushort4 o;
        o.x = f2bf(vv[0] * sc); o.y = f2bf(vv[1] * sc);
        o.z = f2bf(vv[2] * sc); o.w = f2bf(vv[3] * sc);
        *(ushort4*)&out[i * 4] = o;
        return;
    }
    const float* in;
    u16* out;
    int R, C, bx, by, bz = 0;
    if (g < 1024) { in = v; out = vT; R = 2048; C = 1024; bz = g >> 9; g &= 511; bx = g & 15; by = g >> 4; }
    else if (g < 1280) { g -= 1024; in = fcw; out = fcwT; R = 1024; C = 1024; bx = g & 15; by = g >> 4; }
    else if (g < 2304) { g -= 1280; in = w1; out = w1T; R = 1024; C = 4096; bx = g & 63; by = g >> 6; }
    else { g -= 2304; in = w2; out = w2T; R = 4096; C = 1024; bx = g & 15; by = g >> 4; }
    const float* inb = in + (size_t)bz * R * C;
    u16* outb = out + (size_t)bz * R * C;
    int c0 = bx * 64, r0 = by * 64;
    int tr = t >> 4, tc = (t & 15) * 4;
#pragma unroll
    for (int p = 0; p < 4; ++p) {
        int r = tr + p * 16;
        f32x4 vv = *(const f32x4*)&inb[(size_t)(r0 + r) * C + c0 + tc];
        tile[r][tc] = vv[0]; tile[r][tc + 1] = vv[1];
        tile[r][tc + 2] = vv[2]; tile[r][tc + 3] = vv[3];
    }
    __syncthreads();
    int wc = t >> 4, wr = (t & 15) * 4;
#pragma unroll
    for (int p = 0; p < 4; ++p) {
        int cl = wc + p * 16;
        ushort4 o;
        o.x = f2bf(tile[wr + 0][cl]); o.y = f2bf(tile[wr + 1][cl]);
        o.z = f2bf(tile[wr + 2][cl]); o.w = f2bf(tile[wr + 3][cl]);
        *(ushort4*)&outb[(size_t)(c0 + cl) * R + r0 + wr] = o;
    }
}

// ---------------- flash attention v3 (transposed dataflow, 2 q-tiles/wave) -----
__global__ __launch_bounds__(256) void flash_attn(
    const u16* __restrict__ Q, const u16* __restrict__ Kb,
    const u16* __restrict__ VT, const int* __restrict__ mask,
    u16* __restrict__ O) {
    __shared__ u16 kls[2][8192];   // K tile 128x64, fragment order, double-buffered
    __shared__ u16 vls[8192];      // V^T tile 64x128, fragment order
    __shared__ u16 pls[8][2048];   // per-wave x per-qtile P^T 16x128, XOR-swizzled

    const int bid = blockIdx.x;
    const int qt = bid & 15;
    const int h = (bid >> 4) & 15;
    const int n = bid >> 8;
    const int t = threadIdx.x;
    const int w = t >> 6, lane = t & 63;
    const int m16 = lane & 15, quad = lane >> 4;

    const size_t qrowA = (size_t)(n * 2048 + qt * 128 + w * 16 + m16);
    const size_t qrowB = qrowA + 64;
    bf16x8 qfA0 = *(const bf16x8*)&Q[qrowA * 1024 + h * 64 + quad * 8];
    bf16x8 qfA1 = *(const bf16x8*)&Q[qrowA * 1024 + h * 64 + 32 + quad * 8];
    bf16x8 qfB0 = *(const bf16x8*)&Q[qrowB * 1024 + h * 64 + quad * 8];
    bf16x8 qfB1 = *(const bf16x8*)&Q[qrowB * 1024 + h * 64 + 32 + quad * 8];

    const int* maskn = mask + n * 2048;
    int allones;
    {
        int ok = 1;
#pragma unroll
        for (int i = 0; i < 8; ++i) {
            int4 mv = *(const int4*)&maskn[lane * 32 + i * 4];
            ok &= (mv.x != 0) & (mv.y != 0) & (mv.z != 0) & (mv.w != 0);
        }
        allones = __all(ok);
    }

    f32x4 otA[4] = {}, otB[4] = {};
    f32x4 sumA = {}, sumB = {};

    const u16* Kbase = Kb + (size_t)(n * 2048) * 1024 + h * 64;
    const u16* Vbase = VT + (size_t)(n * 1024 + h * 64) * 2048;
    u16* pwA = &pls[w * 2][0];
    u16* pwB = &pls[w * 2 + 1][0];

#pragma unroll
    for (int i = 0; i < 4; ++i) {
        int e = w * 4 + i;
        async_copy16(&Kbase[(size_t)((e >> 1) * 16 + m16) * 1024 + (e & 1) * 32 + quad * 8],
                     &kls[0][e * 512]);
    }
    __syncthreads();

    for (int kt = 0; kt < 16; ++kt) {
        const u16* kcur = kls[kt & 1];
        if (kt + 1 < 16) {
            u16* knext = kls[(kt + 1) & 1];
#pragma unroll
            for (int i = 0; i < 4; ++i) {
                int e = w * 4 + i;
                async_copy16(&Kbase[(size_t)((kt + 1) * 128 + (e >> 1) * 16 + m16) * 1024 +
                                    (e & 1) * 32 + quad * 8], &knext[e * 512]);
            }
        }
#pragma unroll
        for (int i = 0; i < 4; ++i) {
            int e = w * 4 + i;
            async_copy16(&Vbase[(size_t)((e >> 2) * 16 + m16) * 2048 + kt * 128 +
                                (e & 3) * 32 + quad * 8], &vls[e * 512]);
        }

        f32x4 sA[8] = {}, sB[8] = {};
#pragma unroll
        for (int ct = 0; ct < 8; ++ct) {
            bf16x8 a0 = *(const bf16x8*)&kcur[(ct * 2 + 0) * 512 + lane * 8];
            bf16x8 a1 = *(const bf16x8*)&kcur[(ct * 2 + 1) * 512 + lane * 8];
            sA[ct] = MFMA16(a0, qfA0, sA[ct], 0, 0, 0);
            sA[ct] = MFMA16(a1, qfA1, sA[ct], 0, 0, 0);
            sB[ct] = MFMA16(a0, qfB0, sB[ct], 0, 0, 0);
            sB[ct] = MFMA16(a1, qfB1, sB[ct], 0, 0, 0);
        }

        if (allones) {
#pragma unroll
            for (int ct = 0; ct < 8; ++ct) {
                int c = ct * 2 + (quad >> 1);
                int off = m16 * 128 + (((c ^ m16) & 15) << 3) + (quad & 1) * 4;
                {
                    float p0 = __builtin_amdgcn_exp2f(sA[ct][0]);
                    float p1 = __builtin_amdgcn_exp2f(sA[ct][1]);
                    float p2 = __builtin_amdgcn_exp2f(sA[ct][2]);
                    float p3 = __builtin_amdgcn_exp2f(sA[ct][3]);
                    sumA[0] += p0; sumA[1] += p1; sumA[2] += p2; sumA[3] += p3;
                    unsigned lo = __builtin_amdgcn_perm(__float_as_uint(p1), __float_as_uint(p0), 0x07060302);
                    unsigned hi = __builtin_amdgcn_perm(__float_as_uint(p3), __float_as_uint(p2), 0x07060302);
                    *(uint2*)&pwA[off] = make_uint2(lo, hi);
                }
                {
                    float p0 = __builtin_amdgcn_exp2f(sB[ct][0]);
                    float p1 = __builtin_amdgcn_exp2f(sB[ct][1]);
                    float p2 = __builtin_amdgcn_exp2f(sB[ct][2]);
                    float p3 = __builtin_amdgcn_exp2f(sB[ct][3]);
                    sumB[0] += p0; sumB[1] += p1; sumB[2] += p2; sumB[3] += p3;
                    unsigned lo = __builtin_amdgcn_perm(__float_as_uint(p1), __float_as_uint(p0), 0x07060302);
                    unsigned hi = __builtin_amdgcn_perm(__float_as_uint(p3), __float_as_uint(p2), 0x07060302);
                    *(uint2*)&pwB[off] = make_uint2(lo, hi);
                }
            }
        } else {
#pragma unroll
            for (int ct = 0; ct < 8; ++ct) {
                const int4 mv = *(const int4*)&maskn[kt * 128 + ct * 16 + quad * 4];
                int c = ct * 2 + (quad >> 1);
                int off = m16 * 128 + (((c ^ m16) & 15) << 3) + (quad & 1) * 4;
                {
                    float p0 = __builtin_amdgcn_exp2f(sA[ct][0]) * (mv.x ? 1.f : 0.f);
                    float p1 = __builtin_amdgcn_exp2f(sA[ct][1]) * (mv.y ? 1.f : 0.f);
                    float p2 = __builtin_amdgcn_exp2f(sA[ct][2]) * (mv.z ? 1.f : 0.f);
                    float p3 = __builtin_amdgcn_exp2f(sA[ct][3]) * (mv.w ? 1.f : 0.f);
                    sumA[0] += p0; sumA[1] += p1; sumA[2] += p2; sumA[3] += p3;
                    unsigned lo = __builtin_amdgcn_perm(__float_as_uint(p1), __float_as_uint(p0), 0x07060302);
                    unsigned hi = __builtin_amdgcn_perm(__float_as_uint(p3), __float_as_uint(p2), 0x07060302);
                    *(uint2*)&pwA[off] = make_uint2(lo, hi);
                }
                {
                    float p0 = __builtin_amdgcn_exp2f(sB[ct][0]) * (mv.x ? 1.f : 0.f);
                    float p1 = __builtin_amdgcn_exp2f(sB[ct][1]) * (mv.y ? 1.f : 0.f);
                    float p2 = __builtin_amdgcn_exp2f(sB[ct][2]) * (mv.z ? 1.f : 0.f);
                    float p3 = __builtin_amdgcn_exp2f(sB[ct][3]) * (mv.w ? 1.f : 0.f);
                    sumB[0] += p0; sumB[1] += p1; sumB[2] += p2; sumB[3] += p3;
                    unsigned lo = __builtin_amdgcn_perm(__float_as_uint(p1), __float_as_uint(p0), 0x07060302);
                    unsigned hi = __builtin_amdgcn_perm(__float_as_uint(p3), __float_as_uint(p2), 0x07060302);
                    *(uint2*)&pwB[off] = make_uint2(lo, hi);
                }
            }
        }

        __syncthreads();

        bf16x8 pfA[4], pfB[4];
#pragma unroll
        for (int kc2 = 0; kc2 < 4; ++kc2) {
            int off = m16 * 128 + ((((kc2 * 4 + quad) ^ m16) & 15) << 3);
            pfA[kc2] = *(const bf16x8*)&pwA[off];
            pfB[kc2] = *(const bf16x8*)&pwB[off];
        }
#pragma unroll
        for (int kc2 = 0; kc2 < 4; ++kc2) {
#pragma unroll
            for (int dt = 0; dt < 4; ++dt) {
                bf16x8 vf = *(const bf16x8*)&vls[(dt * 4 + kc2) * 512 + lane * 8];
                otA[dt] = MFMA16(vf, pfA[kc2], otA[dt], 0, 0, 0);
                otB[dt] = MFMA16(vf, pfB[kc2], otB[dt], 0, 0, 0);
            }
        }
        __syncthreads();
    }

    float lA = (sumA[0] + sumA[1]) + (sumA[2] + sumA[3]);
    float lB = (sumB[0] + sumB[1]) + (sumB[2] + sumB[3]);
    lA += __shfl_xor(lA, 16); lA += __shfl_xor(lA, 32);
    lB += __shfl_xor(lB, 16); lB += __shfl_xor(lB, 32);
    float invA = 1.f / fmaxf(lA, 1e-30f);
    float invB = 1.f / fmaxf(lB, 1e-30f);

    const size_t obA = qrowA * 1024 + h * 64;
    const size_t obB = qrowB * 1024 + h * 64;
#pragma unroll
    for (int dt = 0; dt < 4; ++dt) {
        unsigned lo = (unsigned)f2bf(otA[dt][0] * invA) | ((unsigned)f2bf(otA[dt][1] * invA) << 16);
        unsigned hi = (unsigned)f2bf(otA[dt][2] * invA) | ((unsigned)f2bf(otA[dt][3] * invA) << 16);
        *(uint2*)&O[obA + dt * 16 + quad * 4] = make_uint2(lo, hi);
        lo = (unsigned)f2bf(otB[dt][0] * invB) | ((unsigned)f2bf(otB[dt][1] * invB) << 16);
        hi = (unsigned)f2bf(otB[dt][2] * invB) | ((unsigned)f2bf(otB[dt][3] * invB) << 16);
        *(uint2*)&O[obB + dt * 16 + quad * 4] = make_uint2(lo, hi);
    }
}

// ---------------- bf16 GEMM 128-tile (2-phase, small-ws fallback only) --------
template <int BM, int BN, int RELU, int OUTBF, int SPLITK>
__global__ __launch_bounds__(256) void gemm_bt(
    const u16* __restrict__ A, const u16* __restrict__ Bt,
    const float* __restrict__ bias, void* __restrict__ Cout,
    void* __restrict__ Cout1, int M, int N, int K) {
    constexpr int MI = BM / 32;
    constexpr int NJ = BN / 32;
    __shared__ u16 sm[2][(BM + BN) * 64];
    const int lane = threadIdx.x & 63;
    const int w = threadIdx.x >> 6;
    const int m16 = lane & 15, quad = lane >> 4;
    const int nBn = N / BN;
    int bid = blockIdx.x;
    int slice = 0;
    if (SPLITK > 1) {
        const int nblk = (M / BM) * nBn;
        slice = bid / nblk;
        bid = bid - slice * nblk;
    }
    const int bm = bid / nBn, bn = bid % nBn;
    const int r2 = w >> 1, c2 = w & 1;
    const int Ks = K / SPLITK;
    const int kOff = slice * Ks;

    const u16* Abase = A + (size_t)(bm * BM + m16) * K + quad * 8;
    const u16* Bbase = Bt + (size_t)(bn * BN + m16) * K + quad * 8;

    auto stage = [&](int buf, int k0) {
        u16* smA = &sm[buf][0];
        u16* smB = smA + BM * 64;
#pragma unroll
        for (int i = 0; i < MI; ++i) {
            int e = w * MI + i;
            async_copy16(&Abase[(size_t)((e >> 1) * 16) * K + k0 + (e & 1) * 32], &smA[e * 512]);
        }
#pragma unroll
        for (int i = 0; i < NJ; ++i) {
            int e = w * NJ + i;
            async_copy16(&Bbase[(size_t)((e >> 1) * 16) * K + k0 + (e & 1) * 32], &smB[e * 512]);
        }
    };

    f32x4 acc[MI][NJ] = {};
    const int nK = Ks >> 6;
    stage(0, kOff);
    __syncthreads();
    for (int kt = 0; kt < nK; ++kt) {
        if (kt + 1 < nK) stage((kt + 1) & 1, kOff + ((kt + 1) << 6));
        const u16* smA = &sm[kt & 1][0];
        const u16* smB = smA + BM * 64;
#pragma unroll
        for (int kc = 0; kc < 2; ++kc) {
            bf16x8 a[MI], b[NJ];
#pragma unroll
            for (int i = 0; i < MI; ++i)
                a[i] = *(const bf16x8*)&smA[((r2 * MI + i) * 2 + kc) * 512 + lane * 8];
#pragma unroll
            for (int j = 0; j < NJ; ++j)
                b[j] = *(const bf16x8*)&smB[((c2 * NJ + j) * 2 + kc) * 512 + lane * 8];
#pragma unroll
            for (int i = 0; i < MI; ++i)
#pragma unroll
                for (int j = 0; j < NJ; ++j)
                    acc[i][j] = MFMA16(a[i], b[j], acc[i][j], 0, 0, 0);
        }
        __syncthreads();
    }
    float bv[NJ];
#pragma unroll
    for (int j = 0; j < NJ; ++j)
        bv[j] = (SPLITK == 1 || slice == 0)
                    ? bias[bn * BN + c2 * (BN / 2) + j * 16 + m16] : 0.f;
    void* Csel = (SPLITK > 1 && slice != 0) ? Cout1 : Cout;
#pragma unroll
    for (int i = 0; i < MI; ++i) {
        int row0 = bm * BM + r2 * (BM / 2) + i * 16 + quad * 4;
#pragma unroll
        for (int j = 0; j < NJ; ++j) {
            int col = bn * BN + c2 * (BN / 2) + j * 16 + m16;
#pragma unroll
            for (int r = 0; r < 4; ++r) {
                float v = acc[i][j][r] + bv[j];
                if (RELU) v = fmaxf(v, 0.f);
                size_t idx = (size_t)(row0 + r) * N + col;
                if (OUTBF) ((u16*)Csel)[idx] = f2bf(v);
                else ((float*)Csel)[idx] = v;
            }
        }
    }
}

// ---------------- 256x256 8-phase GEMM (round-4 schedule, race-free A-split) --
// Units per K-tile: p0=A-even {e0-7,e16-23} (a0 regions, read in ph1/ph5),
// p1=A-odd {e8-15,e24-31} (a1 regions, read ph2/ph6), p2=B-lo e0-15,
// p3=B-hi e16-31. Stage order (1 unit/phase): ph1:T1p3 ph2:T2p0 ph3:T2p1
// ph4:T2p2+gate ph5:T2p3 ph6:T3p0 ph7:T3p1 ph8:T3p2+gate. Gates WAITV(6)
// drain loads staged >=3 phases earlier.
template <int RELU, int OUTBF>
__global__ __launch_bounds__(512, 2) void gemm_8ph(
    const u16* __restrict__ A, const u16* __restrict__ Bt,
    const float* __restrict__ bias, void* __restrict__ Cout,
    int M, int N, int K) {
    __shared__ u16 sm[2][2][16384];   // [buf][A=0/B=1][256x64 fragment order]
    const int t = threadIdx.x;
    const int w = t >> 6, lane = t & 63;
    const int m16 = lane & 15, quad = lane >> 4;
    const int wm = w >> 2, wn = w & 3;
    const int nBn = N >> 8;
    const int bid = blockIdx.x;
    const int bm = bid / nBn, bn = bid % nBn;
    const int nK = K >> 6, nIter = nK >> 1;
    const u16* Abase = A + (size_t)(bm * 256 + m16) * K + quad * 8;
    const u16* Bbase = Bt + (size_t)(bn * 256 + m16) * K + quad * 8;

    auto stage_ht = [&](int kt, int part) {
        if (kt < nK) {
            const u16* base = (part < 2) ? Abase : Bbase;
            u16* lds = &sm[kt & 1][part >> 1][0];
#pragma unroll
            for (int i = 0; i < 2; ++i) {
                int e;
                if (part == 0)      e = i * 16 + w;       // A-even (a0 regions)
                else if (part == 1) e = 8 + i * 16 + w;   // A-odd  (a1 regions)
                else if (part == 2) e = i * 8 + w;        // B-lo
                else                e = 16 + i * 8 + w;   // B-hi
                async_copy16(&base[(size_t)((e >> 1) * 16) * K + (size_t)kt * 64 + (e & 1) * 32],
                             &lds[e * 512]);
            }
        }
    };
    auto ldsA = [&](int buf, int mf, int kc) {
        return *(const bf16x8*)&sm[buf][0][((wm * 8 + mf) * 2 + kc) * 512 + lane * 8];
    };
    auto ldsB = [&](int buf, int nf, int kc) {
        return *(const bf16x8*)&sm[buf][1][((wn * 4 + nf) * 2 + kc) * 512 + lane * 8];
    };

    f32x4 acc[8][4] = {};
    bf16x8 a0[4][2], a1[4][2], b[4][2];

#define QUAD8(Ar, BO, MO)                                                       \
    do {                                                                        \
        __builtin_amdgcn_s_setprio(1);                                          \
        _Pragma("unroll") for (int mi = 0; mi < 4; ++mi)                        \
            _Pragma("unroll") for (int nj = 0; nj < 2; ++nj)                    \
                _Pragma("unroll") for (int kc = 0; kc < 2; ++kc)                \
                    acc[(MO) + mi][(BO) + nj] =                                 \
                        MFMA16(Ar[mi][kc], b[(BO) + nj][kc],                    \
                               acc[(MO) + mi][(BO) + nj], 0, 0, 0);             \
        __builtin_amdgcn_s_setprio(0);                                          \
    } while (0)

    // prologue: tile0 fully + tile1 {A-even, A-odd, B-lo} in flight (14 insts)
    stage_ht(0, 0); stage_ht(0, 1); stage_ht(0, 2); stage_ht(0, 3);
    stage_ht(1, 0); stage_ht(1, 1); stage_ht(1, 2);
    WAITV(6);        // tile0 landed; tile1 A+B-lo in flight
    SBAR();

    for (int it = 0; it < nIter; ++it) {
        const int T1 = 2 * it + 1, T2 = 2 * it + 2, T3 = 2 * it + 3;
        const bool last = (it + 1 == nIter);
        // ph1: bufE reads a0,b01; stage (T1,B-hi)
#pragma unroll
        for (int mf = 0; mf < 4; ++mf) { a0[mf][0] = ldsA(0, mf, 0); a0[mf][1] = ldsA(0, mf, 1); }
#pragma unroll
        for (int nf = 0; nf < 2; ++nf) { b[nf][0] = ldsB(0, nf, 0); b[nf][1] = ldsB(0, nf, 1); }
        stage_ht(T1, 3);
        SBAR(); WAITL0();
        QUAD8(a0, 0, 0);
        SBAR();
        // ph2: bufE reads a1,b23; stage (T2,A-even)  [a0 regions read @ph1 -> safe]
#pragma unroll
        for (int mf = 0; mf < 4; ++mf) { a1[mf][0] = ldsA(0, mf + 4, 0); a1[mf][1] = ldsA(0, mf + 4, 1); }
#pragma unroll
        for (int nf = 0; nf < 2; ++nf) { b[2 + nf][0] = ldsB(0, 2 + nf, 0); b[2 + nf][1] = ldsB(0, 2 + nf, 1); }
        stage_ht(T2, 0);
        SBAR(); WAITL0();
        QUAD8(a0, 2, 0);
        SBAR();
        // ph3: stage (T2,A-odd)  [a1 regions read @ph2 -> safe]
        stage_ht(T2, 1);
        SBAR(); WAITL0();
        QUAD8(a1, 2, 4);
        SBAR();
        // ph4: stage (T2,B-lo); gate bufO(T1) for ph5 (drains through T1,B-hi @ph1)
        stage_ht(T2, 2);
        if (last) { WAITV(0); } else { WAITV(6); }
        SBAR(); WAITL0();
        QUAD8(a1, 0, 4);
        SBAR();
        // ph5: bufO reads a0,b01; stage (T2,B-hi)  [bufE B fully read @ph2]
#pragma unroll
        for (int mf = 0; mf < 4; ++mf) { a0[mf][0] = ldsA(1, mf, 0); a0[mf][1] = ldsA(1, mf, 1); }
#pragma unroll
        for (int nf = 0; nf < 2; ++nf) { b[nf][0] = ldsB(1, nf, 0); b[nf][1] = ldsB(1, nf, 1); }
        stage_ht(T2, 3);
        SBAR(); WAITL0();
        QUAD8(a0, 0, 0);
        SBAR();
        // ph6: bufO reads a1,b23; stage (T3,A-even)  [bufO a0 read @ph5]
#pragma unroll
        for (int mf = 0; mf < 4; ++mf) { a1[mf][0] = ldsA(1, mf + 4, 0); a1[mf][1] = ldsA(1, mf + 4, 1); }
#pragma unroll
        for (int nf = 0; nf < 2; ++nf) { b[2 + nf][0] = ldsB(1, 2 + nf, 0); b[2 + nf][1] = ldsB(1, 2 + nf, 1); }
        stage_ht(T3, 0);
        SBAR(); WAITL0();
        QUAD8(a0, 2, 0);
        SBAR();
        // ph7: stage (T3,A-odd)  [bufO a1 read @ph6]
        stage_ht(T3, 1);
        SBAR(); WAITL0();
        QUAD8(a1, 2, 4);
        SBAR();
        // ph8: stage (T3,B-lo); gate bufE(T2) for next ph1 (drains through T2,B-hi @ph5)
        stage_ht(T3, 2);
        if (last) { WAITV(0); } else { WAITV(6); }
        SBAR(); WAITL0();
        QUAD8(a1, 0, 4);
        SBAR();
    }
#undef QUAD8

    float bv[4];
#pragma unroll
    for (int nf = 0; nf < 4; ++nf)
        bv[nf] = bias[bn * 256 + wn * 64 + nf * 16 + m16];
    const int colb = bn * 256 + wn * 64 + m16;
#pragma unroll
    for (int mf = 0; mf < 8; ++mf) {
        const int row0 = bm * 256 + wm * 128 + mf * 16 + quad * 4;
#pragma unroll
        for (int nf = 0; nf < 4; ++nf) {
#pragma unroll
            for (int r = 0; r < 4; ++r) {
                float vv = acc[mf][nf][r] + bv[nf];
                if (RELU) vv = fmaxf(vv, 0.f);
                size_t idx = (size_t)(row0 + r) * N + colb + nf * 16;
                if (OUTBF) ((u16*)Cout)[idx] = f2bf(vv);
                else ((float*)Cout)[idx] = vv;
            }
        }
    }
}

// ---------------- 128x256 split-K 4-phase GEMM (round-4 schedule) -------------
template <int RELU, int OUTBF, int SPLITK>
__global__ __launch_bounds__(512, 2) void gemm_sk(
    const u16* __restrict__ A, const u16* __restrict__ Bt,
    const float* __restrict__ bias,
    void* __restrict__ C0, void* __restrict__ C1,
    int M, int N, int K) {
    __shared__ u16 smA[2][8192];    // 128x64 per buf
    __shared__ u16 smB[2][16384];   // 256x64 per buf
    const int t = threadIdx.x;
    const int w = t >> 6, lane = t & 63;
    const int m16 = lane & 15, quad = lane >> 4;
    const int wm = w >> 2, wn = w & 3;                 // 2 x 4 wave grid
    const int nBn = N >> 8;
    const int nblk = (M >> 7) * nBn * SPLITK;
    const int o = blockIdx.x;
    const int v = (o & 7) * (nblk >> 3) + (o >> 3);    // XCD-chunked (nblk%8==0)
    const int gsz = nBn * SPLITK;
    const int bm = v / gsz;
    const int rr = v - bm * gsz;
    const int slice = rr / nBn;
    const int bn = rr - slice * nBn;
    const int Ks = K / SPLITK;
    const int nK = Ks >> 6, nIter = nK >> 1;
    const u16* Abase = A + (size_t)(bm * 128 + m16) * K + slice * Ks + quad * 8;
    const u16* Bbase = Bt + (size_t)(bn * 256 + m16) * K + slice * Ks + quad * 8;

    // unit (kt, part): part 0 = A (16 KB), 1 = B-alpha, 2 = B-beta
    auto stage_u = [&](int kt, int part) {
        if (kt < nK) {
#pragma unroll
            for (int i = 0; i < 2; ++i) {
                const int idx = i * 8 + w;
                int e;
                const u16* base;
                u16* lds;
                if (part == 0) {
                    e = idx; base = Abase; lds = &smA[kt & 1][0];
                } else {
                    const int rbs = idx >> 1;
                    const int rb = ((rbs >> 1) << 2) | (rbs & 1) | ((part == 2) ? 2 : 0);
                    e = rb * 2 + (idx & 1);
                    base = Bbase; lds = &smB[kt & 1][0];
                }
                async_copy16(&base[(size_t)((e >> 1) * 16) * K + (size_t)kt * 64 + (e & 1) * 32],
                             &lds[e * 512]);
            }
        }
    };
    auto ldsA = [&](int buf, int mf, int kc) {
        return *(const bf16x8*)&smA[buf][((wm * 4 + mf) * 2 + kc) * 512 + lane * 8];
    };
    auto ldsB = [&](int buf, int nf, int kc) {
        return *(const bf16x8*)&smB[buf][((wn * 4 + nf) * 2 + kc) * 512 + lane * 8];
    };

    f32x4 acc[4][4] = {};
    bf16x8 af[4][2], bf[2][2];

#define QUADS(NO)                                                               \
    do {                                                                        \
        __builtin_amdgcn_s_setprio(1);                                          \
        _Pragma("unroll") for (int mi = 0; mi < 4; ++mi)                        \
            _Pragma("unroll") for (int nj = 0; nj < 2; ++nj)                    \
                _Pragma("unroll") for (int kc = 0; kc < 2; ++kc)                \
                    acc[mi][(NO) + nj] =                                        \
                        MFMA16(af[mi][kc], bf[nj][kc],                          \
                               acc[mi][(NO) + nj], 0, 0, 0);                    \
        __builtin_amdgcn_s_setprio(0);                                          \
    } while (0)

    // prologue: tile0 fully + tile1 A/B-alpha in flight
    stage_u(0, 0); stage_u(0, 1); stage_u(0, 2);
    stage_u(1, 0); stage_u(1, 1);
    WAITV(4);       // tile0 landed
    SBAR();

    for (int it = 0; it < nIter; ++it) {
        const int T1 = 2 * it + 1, T2 = 2 * it + 2, T3 = 2 * it + 3;
        const bool last = (it + 1 == nIter);
        // ph1: bufE reads af + bf(alpha: nf 0,1); stage (T1,B-beta)
#pragma unroll
        for (int mf = 0; mf < 4; ++mf) { af[mf][0] = ldsA(0, mf, 0); af[mf][1] = ldsA(0, mf, 1); }
#pragma unroll
        for (int nf = 0; nf < 2; ++nf) { bf[nf][0] = ldsB(0, nf, 0); bf[nf][1] = ldsB(0, nf, 1); }
        stage_u(T1, 2);
        SBAR(); WAITL0();
        QUADS(0);
        SBAR();
        // ph2: bufE reads bf(beta: nf 2,3); stage (T2,A),(T2,B-alpha); gate bufO(T1)
#pragma unroll
        for (int nf = 0; nf < 2; ++nf) { bf[nf][0] = ldsB(0, 2 + nf, 0); bf[nf][1] = ldsB(0, 2 + nf, 1); }
        stage_u(T2, 0); stage_u(T2, 1);
        if (last) { WAITV(0); } else { WAITV(4); }
        SBAR(); WAITL0();
        QUADS(2);
        SBAR();
        // ph3: bufO reads af + bf(alpha); stage (T2,B-beta)
#pragma unroll
        for (int mf = 0; mf < 4; ++mf) { af[mf][0] = ldsA(1, mf, 0); af[mf][1] = ldsA(1, mf, 1); }
#pragma unroll
        for (int nf = 0; nf < 2; ++nf) { bf[nf][0] = ldsB(1, nf, 0); bf[nf][1] = ldsB(1, nf, 1); }
        stage_u(T2, 2);
        SBAR(); WAITL0();
        QUADS(0);
        SBAR();
        // ph4: bufO reads bf(beta); stage (T3,A),(T3,B-alpha); gate bufE(T2)
#pragma unroll
        for (int nf = 0; nf < 2; ++nf) { bf[nf][0] = ldsB(1, 2 + nf, 0); bf[nf][1] = ldsB(1, 2 + nf, 1); }
        stage_u(T3, 0); stage_u(T3, 1);
        if (last) { WAITV(0); } else { WAITV(4); }
        SBAR(); WAITL0();
        QUADS(2);
        SBAR();
    }
#undef QUADS

    float bv[4];
#pragma unroll
    for (int nf = 0; nf < 4; ++nf)
        bv[nf] = (SPLITK == 1 || slice == 0)
                     ? bias[bn * 256 + wn * 64 + nf * 16 + m16] : 0.f;
    void* Csel = (SPLITK > 1 && slice != 0) ? C1 : C0;
    const int colb = bn * 256 + wn * 64 + m16;
#pragma unroll
    for (int mf = 0; mf < 4; ++mf) {
        const int row0 = bm * 128 + wm * 64 + mf * 16 + quad * 4;
#pragma unroll
        for (int nf = 0; nf < 4; ++nf) {
#pragma unroll
            for (int r = 0; r < 4; ++r) {
                float vv = acc[mf][nf][r] + bv[nf];
                if (RELU) vv = fmaxf(vv, 0.f);
                size_t idx = (size_t)(row0 + r) * N + colb + nf * 16;
                if (OUTBF) ((u16*)Csel)[idx] = f2bf(vv);
                else ((float*)Csel)[idx] = vv;
            }
        }
    }
}

// ---------------- residual + layernorm (row = 1024) ----------------
// out = LN(x + x2 + res); x2 optional split-K partial. RESBF: res is bf16.
// out_f32 optional.
template <int RESBF>
__global__ __launch_bounds__(256) void ln_residual(
    const float* __restrict__ x, const float* x2,
    const void* __restrict__ res,
    const float* __restrict__ g, const float* __restrict__ b,
    float* out_f32, u16* __restrict__ out_bf16) {
    __shared__ float smr[8];
    int row = blockIdx.x;
    int t = threadIdx.x;
    f32x4 xv = *(const f32x4*)&x[(size_t)row * 1024 + t * 4];
    f32x4 rv;
    if (RESBF) {
        ushort4 rb = *(const ushort4*)&((const u16*)res)[(size_t)row * 1024 + t * 4];
        rv[0] = bf2f(rb.x); rv[1] = bf2f(rb.y); rv[2] = bf2f(rb.z); rv[3] = bf2f(rb.w);
    } else {
        rv = *(const f32x4*)&((const float*)res)[(size_t)row * 1024 + t * 4];
    }
    xv += rv;
    if (x2) xv += *(const f32x4*)&x2[(size_t)row * 1024 + t * 4];
    float s = xv[0] + xv[1] + xv[2] + xv[3];
    float ss = xv[0] * xv[0] + xv[1] * xv[1] + xv[2] * xv[2] + xv[3] * xv[3];
#pragma unroll
    for (int d = 1; d < 64; d <<= 1) {
        s += __shfl_xor(s, d);
        ss += __shfl_xor(ss, d);
    }
    int w = t >> 6, lane = t & 63;
    if (lane == 0) { smr[w] = s; smr[4 + w] = ss; }
    __syncthreads();
    s = smr[0] + smr[1] + smr[2] + smr[3];
    ss = smr[4] + smr[5] + smr[6] + smr[7];
    float mu = s * (1.f / 1024.f);
    float var = ss * (1.f / 1024.f) - mu * mu;
    float rs = rsqrtf(var + 1e-5f);
    f32x4 gv = *(const f32x4*)&g[t * 4];
    f32x4 bv = *(const f32x4*)&b[t * 4];
    f32x4 y;
#pragma unroll
    for (int i = 0; i < 4; ++i) y[i] = (xv[i] - mu) * rs * gv[i] + bv[i];
    if (out_f32) *(f32x4*)&out_f32[(size_t)row * 1024 + t * 4] = y;
    if (out_bf16) {
        ushort4 o;
        o.x = f2bf(y[0]); o.y = f2bf(y[1]); o.z = f2bf(y[2]); o.w = f2bf(y[3]);
        *(ushort4*)&out_bf16[(size_t)row * 1024 + t * 4] = o;
    }
}

extern "C" void kernel_launch(void* const* d_in, const int* in_sizes, int n_in,
                              void* d_out, int out_size, void* d_ws, size_t ws_size,
                              hipStream_t stream) {
    const float* q = (const float*)d_in[0];
    const float* k = (const float*)d_in[1];
    const float* v = (const float*)d_in[2];
    const int* mask = (const int*)d_in[3];
    const float* fc_b = (const float*)d_in[5];
    const float* ln1_g = (const float*)d_in[6];
    const float* ln1_b = (const float*)d_in[7];
    const float* ff_b1 = (const float*)d_in[9];
    const float* ff_b2 = (const float*)d_in[11];
    const float* ln2_g = (const float*)d_in[12];
    const float* ln2_b = (const float*)d_in[13];
    const float* fc_w = (const float*)d_in[4];
    const float* ff_w1 = (const float*)d_in[8];
    const float* ff_w2 = (const float*)d_in[10];

    char* ws = (char*)d_ws;
    const size_t MB = 1024 * 1024;
    u16* qbf = (u16*)(ws + 0);          // 8 MB (pre-scaled)
    u16* kbf = (u16*)(ws + 8 * MB);     // 8 MB
    u16* vT  = (u16*)(ws + 16 * MB);    // 8 MB
    u16* ao  = (u16*)(ws + 24 * MB);    // 8 MB
    u16* hbuf = (u16*)(ws + 0);         // 32 MB (after attention+out-proj)
    u16* fcwT = (u16*)(ws + 32 * MB);   // 2 MB
    u16* w1T  = (u16*)(ws + 34 * MB);   // 8 MB
    u16* w2T  = (u16*)(ws + 42 * MB);   // 8 MB
    float* attn_raw = (float*)(ws + 50 * MB); // 16 MB (out-proj slice 0)
    float* fc_raw   = (float*)(ws + 50 * MB); // FFN2 slice 0 (attn_raw dead)
    u16* x1bf   = (u16*)(ws + 82 * MB);       // 8 MB (LN1 out, bf16 only)
    float* attn_rawB = (float*)(ws + 0);      // 16 MB (out-proj slice 1; dead region)
    float* fcB  = (float*)(ws + 90 * MB);     // 16 MB (FFN2 slice 1)
    const bool big = ws_size >= 106 * MB;

    const float k2 = 0.03125f * 1.44269504088896340736f; // 1/sqrt(1024)*log2(e)

    // preprocessing: single fused launch (2 casts + 4 transposes)
    prep_all<<<11520, 256, 0, stream>>>(q, qbf, k2, k, kbf, v, vT,
                                        fc_w, fcwT, ff_w1, w1T, ff_w2, w2T);

    // attention
    flash_attn<<<512, 256, 0, stream>>>(qbf, kbf, vT, mask, ao);

    // out-proj: 128x256 split-K=2 4-phase (grid 256 = 1 block/CU, 8 waves)
    gemm_sk<0, 0, 2><<<256, 512, 0, stream>>>(
        ao, fcwT, fc_b, attn_raw, attn_rawB, 4096, 1024, 1024);
    ln_residual<0><<<4096, 256, 0, stream>>>(attn_raw, attn_rawB, q, ln1_g, ln1_b,
                                             nullptr, x1bf);

    // FFN1: 256x256 8-phase (grid 256, round-4 schedule)
    gemm_8ph<1, 1><<<256, 512, 0, stream>>>(
        x1bf, w1T, ff_b1, hbuf, 4096, 4096, 1024);

    // FFN2: 128x256 split-K=2 4-phase (grid 256)
    if (big) {
        gemm_sk<0, 0, 2><<<256, 512, 0, stream>>>(
            hbuf, w2T, ff_b2, fc_raw, fcB, 4096, 1024, 4096);
        ln_residual<1><<<4096, 256, 0, stream>>>(fc_raw, fcB, x1bf, ln2_g, ln2_b,
                                                 (float*)d_out, (u16*)nullptr);
    } else {
        gemm_bt<64, 128, 0, 0, 1><<<64 * 8, 256, 0, stream>>>(
            hbuf, w2T, ff_b2, fc_raw, nullptr, 4096, 1024, 4096);
        ln_residual<1><<<4096, 256, 0, stream>>>(fc_raw, nullptr, x1bf, ln2_g, ln2_b,
                                                 (float*)d_out, (u16*)nullptr);
    }
}

// Round 8
// 350.649 us; speedup vs baseline: 1.1266x; 1.0008x over previous
//
#include <hip/hip_runtime.h>
#include <stdint.h>

typedef unsigned short u16;
typedef __bf16 bf16x8 __attribute__((ext_vector_type(8), may_alias));
typedef float f32x4 __attribute__((ext_vector_type(4), may_alias));

typedef void __attribute__((address_space(1))) as1_void;
typedef void __attribute__((address_space(3))) as3_void;

#define MFMA16 __builtin_amdgcn_mfma_f32_16x16x32_bf16

#define SBAR()                                \
    do {                                      \
        asm volatile("" ::: "memory");        \
        __builtin_amdgcn_s_barrier();         \
        asm volatile("" ::: "memory");        \
    } while (0)
#define WAITV(n) asm volatile("s_waitcnt vmcnt(" #n ")" ::: "memory")
#define WAITL(n) asm volatile("s_waitcnt lgkmcnt(" #n ")" ::: "memory")

__device__ __forceinline__ void async_copy16(const void* g, void* l) {
    __builtin_amdgcn_global_load_lds((as1_void*)g, (as3_void*)l, 16, 0, 0);
}

// round-to-nearest-even fp32 -> bf16 bits
__device__ __forceinline__ u16 f2bf(float f) {
    union { float f; unsigned u; } c; c.f = f;
    unsigned u = c.u;
    u += 0x7fffu + ((u >> 16) & 1u);
    return (u16)(u >> 16);
}
__device__ __forceinline__ float bf2f(u16 u) {
    return __uint_as_float((unsigned)u << 16);
}

// ---------------- fused preprocessing: 2 casts + 4 transposes, one launch ----
__global__ __launch_bounds__(256) void prep_all(
    const float* __restrict__ q, u16* __restrict__ qbf, float qscale,
    const float* __restrict__ k, u16* __restrict__ kbf,
    const float* __restrict__ v, u16* __restrict__ vT,
    const float* __restrict__ fcw, u16* __restrict__ fcwT,
    const float* __restrict__ w1, u16* __restrict__ w1T,
    const float* __restrict__ w2, u16* __restrict__ w2T) {
    __shared__ float tile[64][65];
    int g = blockIdx.x;
    int t = threadIdx.x;
    if (g >= 3328) {
        g -= 3328;
        const float* in;
        u16* out;
        float sc;
        if (g < 4096) { in = q; out = qbf; sc = qscale; }
        else { g -= 4096; in = k; out = kbf; sc = 1.0f; }
        size_t i = (size_t)g * 256 + t;
        f32x4 vv = *(const f32x4*)&in[i * 4];
        ushort4 o;
        o.x = f2bf(vv[0] * sc); o.y = f2bf(vv[1] * sc);
        o.z = f2bf(vv[2] * sc); o.w = f2bf(vv[3] * sc);
        *(ushort4*)&out[i * 4] = o;
        return;
    }
    const float* in;
    u16* out;
    int R, C, bx, by, bz = 0;
    if (g < 1024) { in = v; out = vT; R = 2048; C = 1024; bz = g >> 9; g &= 511; bx = g & 15; by = g >> 4; }
    else if (g < 1280) { g -= 1024; in = fcw; out = fcwT; R = 1024; C = 1024; bx = g & 15; by = g >> 4; }
    else if (g < 2304) { g -= 1280; in = w1; out = w1T; R = 1024; C = 4096; bx = g & 63; by = g >> 6; }
    else { g -= 2304; in = w2; out = w2T; R = 4096; C = 1024; bx = g & 15; by = g >> 4; }
    const float* inb = in + (size_t)bz * R * C;
    u16* outb = out + (size_t)bz * R * C;
    int c0 = bx * 64, r0 = by * 64;
    int tr = t >> 4, tc = (t & 15) * 4;
#pragma unroll
    for (int p = 0; p < 4; ++p) {
        int r = tr + p * 16;
        f32x4 vv = *(const f32x4*)&inb[(size_t)(r0 + r) * C + c0 + tc];
        tile[r][tc] = vv[0]; tile[r][tc + 1] = vv[1];
        tile[r][tc + 2] = vv[2]; tile[r][tc + 3] = vv[3];
    }
    __syncthreads();
    int wc = t >> 4, wr = (t & 15) * 4;
#pragma unroll
    for (int p = 0; p < 4; ++p) {
        int cl = wc + p * 16;
        ushort4 o;
        o.x = f2bf(tile[wr + 0][cl]); o.y = f2bf(tile[wr + 1][cl]);
        o.z = f2bf(tile[wr + 2][cl]); o.w = f2bf(tile[wr + 3][cl]);
        *(ushort4*)&outb[(size_t)(c0 + cl) * R + r0 + wr] = o;
    }
}

// ---------------- flash attention v3 (transposed dataflow, 2 q-tiles/wave) -----
__global__ __launch_bounds__(256) void flash_attn(
    const u16* __restrict__ Q, const u16* __restrict__ Kb,
    const u16* __restrict__ VT, const int* __restrict__ mask,
    u16* __restrict__ O) {
    __shared__ u16 kls[2][8192];   // K tile 128x64, fragment order, double-buffered
    __shared__ u16 vls[8192];      // V^T tile 64x128, fragment order
    __shared__ u16 pls[8][2048];   // per-wave x per-qtile P^T 16x128, XOR-swizzled

    const int bid = blockIdx.x;
    const int qt = bid & 15;
    const int h = (bid >> 4) & 15;
    const int n = bid >> 8;
    const int t = threadIdx.x;
    const int w = t >> 6, lane = t & 63;
    const int m16 = lane & 15, quad = lane >> 4;

    const size_t qrowA = (size_t)(n * 2048 + qt * 128 + w * 16 + m16);
    const size_t qrowB = qrowA + 64;
    bf16x8 qfA0 = *(const bf16x8*)&Q[qrowA * 1024 + h * 64 + quad * 8];
    bf16x8 qfA1 = *(const bf16x8*)&Q[qrowA * 1024 + h * 64 + 32 + quad * 8];
    bf16x8 qfB0 = *(const bf16x8*)&Q[qrowB * 1024 + h * 64 + quad * 8];
    bf16x8 qfB1 = *(const bf16x8*)&Q[qrowB * 1024 + h * 64 + 32 + quad * 8];

    const int* maskn = mask + n * 2048;
    int allones;
    {
        int ok = 1;
#pragma unroll
        for (int i = 0; i < 8; ++i) {
            int4 mv = *(const int4*)&maskn[lane * 32 + i * 4];
            ok &= (mv.x != 0) & (mv.y != 0) & (mv.z != 0) & (mv.w != 0);
        }
        allones = __all(ok);
    }

    f32x4 otA[4] = {}, otB[4] = {};
    f32x4 sumA = {}, sumB = {};

    const u16* Kbase = Kb + (size_t)(n * 2048) * 1024 + h * 64;
    const u16* Vbase = VT + (size_t)(n * 1024 + h * 64) * 2048;
    u16* pwA = &pls[w * 2][0];
    u16* pwB = &pls[w * 2 + 1][0];

#pragma unroll
    for (int i = 0; i < 4; ++i) {
        int e = w * 4 + i;
        async_copy16(&Kbase[(size_t)((e >> 1) * 16 + m16) * 1024 + (e & 1) * 32 + quad * 8],
                     &kls[0][e * 512]);
    }
    __syncthreads();

    for (int kt = 0; kt < 16; ++kt) {
        const u16* kcur = kls[kt & 1];
        if (kt + 1 < 16) {
            u16* knext = kls[(kt + 1) & 1];
#pragma unroll
            for (int i = 0; i < 4; ++i) {
                int e = w * 4 + i;
                async_copy16(&Kbase[(size_t)((kt + 1) * 128 + (e >> 1) * 16 + m16) * 1024 +
                                    (e & 1) * 32 + quad * 8], &knext[e * 512]);
            }
        }
#pragma unroll
        for (int i = 0; i < 4; ++i) {
            int e = w * 4 + i;
            async_copy16(&Vbase[(size_t)((e >> 2) * 16 + m16) * 2048 + kt * 128 +
                                (e & 3) * 32 + quad * 8], &vls[e * 512]);
        }

        f32x4 sA[8] = {}, sB[8] = {};
#pragma unroll
        for (int ct = 0; ct < 8; ++ct) {
            bf16x8 a0 = *(const bf16x8*)&kcur[(ct * 2 + 0) * 512 + lane * 8];
            bf16x8 a1 = *(const bf16x8*)&kcur[(ct * 2 + 1) * 512 + lane * 8];
            sA[ct] = MFMA16(a0, qfA0, sA[ct], 0, 0, 0);
            sA[ct] = MFMA16(a1, qfA1, sA[ct], 0, 0, 0);
            sB[ct] = MFMA16(a0, qfB0, sB[ct], 0, 0, 0);
            sB[ct] = MFMA16(a1, qfB1, sB[ct], 0, 0, 0);
        }

        if (allones) {
#pragma unroll
            for (int ct = 0; ct < 8; ++ct) {
                int c = ct * 2 + (quad >> 1);
                int off = m16 * 128 + (((c ^ m16) & 15) << 3) + (quad & 1) * 4;
                {
                    float p0 = __builtin_amdgcn_exp2f(sA[ct][0]);
                    float p1 = __builtin_amdgcn_exp2f(sA[ct][1]);
                    float p2 = __builtin_amdgcn_exp2f(sA[ct][2]);
                    float p3 = __builtin_amdgcn_exp2f(sA[ct][3]);
                    sumA[0] += p0; sumA[1] += p1; sumA[2] += p2; sumA[3] += p3;
                    unsigned lo = __builtin_amdgcn_perm(__float_as_uint(p1), __float_as_uint(p0), 0x07060302);
                    unsigned hi = __builtin_amdgcn_perm(__float_as_uint(p3), __float_as_uint(p2), 0x07060302);
                    *(uint2*)&pwA[off] = make_uint2(lo, hi);
                }
                {
                    float p0 = __builtin_amdgcn_exp2f(sB[ct][0]);
                    float p1 = __builtin_amdgcn_exp2f(sB[ct][1]);
                    float p2 = __builtin_amdgcn_exp2f(sB[ct][2]);
                    float p3 = __builtin_amdgcn_exp2f(sB[ct][3]);
                    sumB[0] += p0; sumB[1] += p1; sumB[2] += p2; sumB[3] += p3;
                    unsigned lo = __builtin_amdgcn_perm(__float_as_uint(p1), __float_as_uint(p0), 0x07060302);
                    unsigned hi = __builtin_amdgcn_perm(__float_as_uint(p3), __float_as_uint(p2), 0x07060302);
                    *(uint2*)&pwB[off] = make_uint2(lo, hi);
                }
            }
        } else {
#pragma unroll
            for (int ct = 0; ct < 8; ++ct) {
                const int4 mv = *(const int4*)&maskn[kt * 128 + ct * 16 + quad * 4];
                int c = ct * 2 + (quad >> 1);
                int off = m16 * 128 + (((c ^ m16) & 15) << 3) + (quad & 1) * 4;
                {
                    float p0 = __builtin_amdgcn_exp2f(sA[ct][0]) * (mv.x ? 1.f : 0.f);
                    float p1 = __builtin_amdgcn_exp2f(sA[ct][1]) * (mv.y ? 1.f : 0.f);
                    float p2 = __builtin_amdgcn_exp2f(sA[ct][2]) * (mv.z ? 1.f : 0.f);
                    float p3 = __builtin_amdgcn_exp2f(sA[ct][3]) * (mv.w ? 1.f : 0.f);
                    sumA[0] += p0; sumA[1] += p1; sumA[2] += p2; sumA[3] += p3;
                    unsigned lo = __builtin_amdgcn_perm(__float_as_uint(p1), __float_as_uint(p0), 0x07060302);
                    unsigned hi = __builtin_amdgcn_perm(__float_as_uint(p3), __float_as_uint(p2), 0x07060302);
                    *(uint2*)&pwA[off] = make_uint2(lo, hi);
                }
                {
                    float p0 = __builtin_amdgcn_exp2f(sB[ct][0]) * (mv.x ? 1.f : 0.f);
                    float p1 = __builtin_amdgcn_exp2f(sB[ct][1]) * (mv.y ? 1.f : 0.f);
                    float p2 = __builtin_amdgcn_exp2f(sB[ct][2]) * (mv.z ? 1.f : 0.f);
                    float p3 = __builtin_amdgcn_exp2f(sB[ct][3]) * (mv.w ? 1.f : 0.f);
                    sumB[0] += p0; sumB[1] += p1; sumB[2] += p2; sumB[3] += p3;
                    unsigned lo = __builtin_amdgcn_perm(__float_as_uint(p1), __float_as_uint(p0), 0x07060302);
                    unsigned hi = __builtin_amdgcn_perm(__float_as_uint(p3), __float_as_uint(p2), 0x07060302);
                    *(uint2*)&pwB[off] = make_uint2(lo, hi);
                }
            }
        }

        __syncthreads();

        bf16x8 pfA[4], pfB[4];
#pragma unroll
        for (int kc2 = 0; kc2 < 4; ++kc2) {
            int off = m16 * 128 + ((((kc2 * 4 + quad) ^ m16) & 15) << 3);
            pfA[kc2] = *(const bf16x8*)&pwA[off];
            pfB[kc2] = *(const bf16x8*)&pwB[off];
        }
#pragma unroll
        for (int kc2 = 0; kc2 < 4; ++kc2) {
#pragma unroll
            for (int dt = 0; dt < 4; ++dt) {
                bf16x8 vf = *(const bf16x8*)&vls[(dt * 4 + kc2) * 512 + lane * 8];
                otA[dt] = MFMA16(vf, pfA[kc2], otA[dt], 0, 0, 0);
                otB[dt] = MFMA16(vf, pfB[kc2], otB[dt], 0, 0, 0);
            }
        }
        __syncthreads();
    }

    float lA = (sumA[0] + sumA[1]) + (sumA[2] + sumA[3]);
    float lB = (sumB[0] + sumB[1]) + (sumB[2] + sumB[3]);
    lA += __shfl_xor(lA, 16); lA += __shfl_xor(lA, 32);
    lB += __shfl_xor(lB, 16); lB += __shfl_xor(lB, 32);
    float invA = 1.f / fmaxf(lA, 1e-30f);
    float invB = 1.f / fmaxf(lB, 1e-30f);

    const size_t obA = qrowA * 1024 + h * 64;
    const size_t obB = qrowB * 1024 + h * 64;
#pragma unroll
    for (int dt = 0; dt < 4; ++dt) {
        unsigned lo = (unsigned)f2bf(otA[dt][0] * invA) | ((unsigned)f2bf(otA[dt][1] * invA) << 16);
        unsigned hi = (unsigned)f2bf(otA[dt][2] * invA) | ((unsigned)f2bf(otA[dt][3] * invA) << 16);
        *(uint2*)&O[obA + dt * 16 + quad * 4] = make_uint2(lo, hi);
        lo = (unsigned)f2bf(otB[dt][0] * invB) | ((unsigned)f2bf(otB[dt][1] * invB) << 16);
        hi = (unsigned)f2bf(otB[dt][2] * invB) | ((unsigned)f2bf(otB[dt][3] * invB) << 16);
        *(uint2*)&O[obB + dt * 16 + quad * 4] = make_uint2(lo, hi);
    }
}

// ---------------- bf16 GEMM 128-tile (2-phase, small-ws fallback only) --------
template <int BM, int BN, int RELU, int OUTBF, int SPLITK>
__global__ __launch_bounds__(256) void gemm_bt(
    const u16* __restrict__ A, const u16* __restrict__ Bt,
    const float* __restrict__ bias, void* __restrict__ Cout,
    void* __restrict__ Cout1, int M, int N, int K) {
    constexpr int MI = BM / 32;
    constexpr int NJ = BN / 32;
    __shared__ u16 sm[2][(BM + BN) * 64];
    const int lane = threadIdx.x & 63;
    const int w = threadIdx.x >> 6;
    const int m16 = lane & 15, quad = lane >> 4;
    const int nBn = N / BN;
    int bid = blockIdx.x;
    int slice = 0;
    if (SPLITK > 1) {
        const int nblk = (M / BM) * nBn;
        slice = bid / nblk;
        bid = bid - slice * nblk;
    }
    const int bm = bid / nBn, bn = bid % nBn;
    const int r2 = w >> 1, c2 = w & 1;
    const int Ks = K / SPLITK;
    const int kOff = slice * Ks;

    const u16* Abase = A + (size_t)(bm * BM + m16) * K + quad * 8;
    const u16* Bbase = Bt + (size_t)(bn * BN + m16) * K + quad * 8;

    auto stage = [&](int buf, int k0) {
        u16* smA = &sm[buf][0];
        u16* smB = smA + BM * 64;
#pragma unroll
        for (int i = 0; i < MI; ++i) {
            int e = w * MI + i;
            async_copy16(&Abase[(size_t)((e >> 1) * 16) * K + k0 + (e & 1) * 32], &smA[e * 512]);
        }
#pragma unroll
        for (int i = 0; i < NJ; ++i) {
            int e = w * NJ + i;
            async_copy16(&Bbase[(size_t)((e >> 1) * 16) * K + k0 + (e & 1) * 32], &smB[e * 512]);
        }
    };

    f32x4 acc[MI][NJ] = {};
    const int nK = Ks >> 6;
    stage(0, kOff);
    __syncthreads();
    for (int kt = 0; kt < nK; ++kt) {
        if (kt + 1 < nK) stage((kt + 1) & 1, kOff + ((kt + 1) << 6));
        const u16* smA = &sm[kt & 1][0];
        const u16* smB = smA + BM * 64;
#pragma unroll
        for (int kc = 0; kc < 2; ++kc) {
            bf16x8 a[MI], b[NJ];
#pragma unroll
            for (int i = 0; i < MI; ++i)
                a[i] = *(const bf16x8*)&smA[((r2 * MI + i) * 2 + kc) * 512 + lane * 8];
#pragma unroll
            for (int j = 0; j < NJ; ++j)
                b[j] = *(const bf16x8*)&smB[((c2 * NJ + j) * 2 + kc) * 512 + lane * 8];
#pragma unroll
            for (int i = 0; i < MI; ++i)
#pragma unroll
                for (int j = 0; j < NJ; ++j)
                    acc[i][j] = MFMA16(a[i], b[j], acc[i][j], 0, 0, 0);
        }
        __syncthreads();
    }
    float bv[NJ];
#pragma unroll
    for (int j = 0; j < NJ; ++j)
        bv[j] = (SPLITK == 1 || slice == 0)
                    ? bias[bn * BN + c2 * (BN / 2) + j * 16 + m16] : 0.f;
    void* Csel = (SPLITK > 1 && slice != 0) ? Cout1 : Cout;
#pragma unroll
    for (int i = 0; i < MI; ++i) {
        int row0 = bm * BM + r2 * (BM / 2) + i * 16 + quad * 4;
#pragma unroll
        for (int j = 0; j < NJ; ++j) {
            int col = bn * BN + c2 * (BN / 2) + j * 16 + m16;
#pragma unroll
            for (int r = 0; r < 4; ++r) {
                float v = acc[i][j][r] + bv[j];
                if (RELU) v = fmaxf(v, 0.f);
                size_t idx = (size_t)(row0 + r) * N + col;
                if (OUTBF) ((u16*)Csel)[idx] = f2bf(v);
                else ((float*)Csel)[idx] = v;
            }
        }
    }
}

// ---------------- 256x256 8-phase GEMM (single-barrier fused phases) ----------
// Phase = [vmcnt gate (ph1/ph5)]; BARRIER; ds_reads; stage 1 unit; 16 MFMA.
// NO explicit lgkmcnt(0): compiler emits counted lgkm waits per consumer, so
// the LDS drain overlaps the MFMA cluster. Reads are same-phase-as-first-use
// -> all operand register sets single-buffered WAR-safe (a0:ph1->rewr ph5;
// b01:ph1,Q4@ph4->ph5; a1:ph2->ph6; b23:ph2,ph3->ph6).
// Stage ledger (2 insts/unit): ph1:T1p3 ph2:T2p0 ph3:T2p1 ph4:T2p2 ph5:T2p3
// ph6:T3p0 ph7:T3p1 ph8:T3p2. Gates: ph1 WAITV(6) (bufE valid: newest 6 =
// T1p0-2), ph5 last?0:6 (bufO valid: newest 6 = T2p0-2). Stage-vs-read WAR:
// every staged region's reads completed in an earlier phase (forced by that
// phase's MFMA issue); deferred case a1 (read ph2/ph6, region staged ph3/ph7)
// protected by WAITL(0) before that stage (off the MFMA path, expected-free).
template <int RELU, int OUTBF>
__global__ __launch_bounds__(512, 2) void gemm_8ph(
    const u16* __restrict__ A, const u16* __restrict__ Bt,
    const float* __restrict__ bias, void* __restrict__ Cout,
    int M, int N, int K) {
    __shared__ u16 sm[2][2][16384];   // [buf][A=0/B=1][256x64 fragment order]
    const int t = threadIdx.x;
    const int w = t >> 6, lane = t & 63;
    const int m16 = lane & 15, quad = lane >> 4;
    const int wm = w >> 2, wn = w & 3;
    const int nBn = N >> 8;
    const int bid = blockIdx.x;
    const int bm = bid / nBn, bn = bid % nBn;
    const int nK = K >> 6, nIter = nK >> 1;
    const u16* Abase = A + (size_t)(bm * 256 + m16) * K + quad * 8;
    const u16* Bbase = Bt + (size_t)(bn * 256 + m16) * K + quad * 8;

    auto stage_ht = [&](int kt, int part) {
        if (kt < nK) {
            const u16* base = (part < 2) ? Abase : Bbase;
            u16* lds = &sm[kt & 1][part >> 1][0];
#pragma unroll
            for (int i = 0; i < 2; ++i) {
                int e;
                if (part == 0)      e = i * 16 + w;       // A-even (a0 regions)
                else if (part == 1) e = 8 + i * 16 + w;   // A-odd  (a1 regions)
                else if (part == 2) e = i * 8 + w;        // B-lo
                else                e = 16 + i * 8 + w;   // B-hi
                async_copy16(&base[(size_t)((e >> 1) * 16) * K + (size_t)kt * 64 + (e & 1) * 32],
                             &lds[e * 512]);
            }
        }
    };
    auto ldsA = [&](int buf, int mf, int kc) {
        return *(const bf16x8*)&sm[buf][0][((wm * 8 + mf) * 2 + kc) * 512 + lane * 8];
    };
    auto ldsB = [&](int buf, int nf, int kc) {
        return *(const bf16x8*)&sm[buf][1][((wn * 4 + nf) * 2 + kc) * 512 + lane * 8];
    };

    f32x4 acc[8][4] = {};
    bf16x8 a0[4][2], a1[4][2], b01[2][2], b23[2][2];

#define RD_A0(buf)                                                              \
    _Pragma("unroll") for (int mf = 0; mf < 4; ++mf) {                          \
        a0[mf][0] = ldsA(buf, mf, 0); a0[mf][1] = ldsA(buf, mf, 1); }
#define RD_A1(buf)                                                              \
    _Pragma("unroll") for (int mf = 0; mf < 4; ++mf) {                          \
        a1[mf][0] = ldsA(buf, mf + 4, 0); a1[mf][1] = ldsA(buf, mf + 4, 1); }
#define RD_B01(buf)                                                             \
    _Pragma("unroll") for (int nf = 0; nf < 2; ++nf) {                          \
        b01[nf][0] = ldsB(buf, nf, 0); b01[nf][1] = ldsB(buf, nf, 1); }
#define RD_B23(buf)                                                             \
    _Pragma("unroll") for (int nf = 0; nf < 2; ++nf) {                          \
        b23[nf][0] = ldsB(buf, 2 + nf, 0); b23[nf][1] = ldsB(buf, 2 + nf, 1); }
#define QUAD8(Ar, Br, MO, NO)                                                   \
    do {                                                                        \
        __builtin_amdgcn_s_setprio(1);                                          \
        _Pragma("unroll") for (int mi = 0; mi < 4; ++mi)                        \
            _Pragma("unroll") for (int nj = 0; nj < 2; ++nj)                    \
                _Pragma("unroll") for (int kc = 0; kc < 2; ++kc)                \
                    acc[(MO) + mi][(NO) + nj] =                                 \
                        MFMA16(Ar[mi][kc], Br[nj][kc],                          \
                               acc[(MO) + mi][(NO) + nj], 0, 0, 0);             \
        __builtin_amdgcn_s_setprio(0);                                          \
    } while (0)

    // prologue: tile0 fully + tile1 {p0,p1,p2} in flight (14 insts); ph1 gates.
    stage_ht(0, 0); stage_ht(0, 1); stage_ht(0, 2); stage_ht(0, 3);
    stage_ht(1, 0); stage_ht(1, 1); stage_ht(1, 2);

    for (int it = 0; it < nIter; ++it) {
        const int T1 = 2 * it + 1, T2 = 2 * it + 2, T3 = 2 * it + 3;
        const bool last = (it + 1 == nIter);
        // ph1: gate bufE; reads a0,b01(E); stage T1,B-hi; Q1
        WAITV(6);
        SBAR();
        RD_A0(0); RD_B01(0);
        stage_ht(T1, 3);
        QUAD8(a0, b01, 0, 0);
        // ph2: reads a1 THEN b23 (order matters: Q2's b23 wait drains a1);
        //      stage T2,A-even; Q2
        SBAR();
        RD_A1(0); RD_B23(0);
        stage_ht(T2, 0);
        QUAD8(a0, b23, 0, 2);
        // ph3: WAITL(0) guards a1 region (staged now) against late a1 reads;
        //      stage T2,A-odd; Q3
        SBAR();
        WAITL(0);
        stage_ht(T2, 1);
        QUAD8(a1, b23, 4, 2);
        // ph4: stage T2,B-lo; Q4
        SBAR();
        stage_ht(T2, 2);
        QUAD8(a1, b01, 4, 0);
        // ph5: gate bufO; reads a0,b01(O); stage T2,B-hi; Q1'
        if (last) { WAITV(0); } else { WAITV(6); }
        SBAR();
        RD_A0(1); RD_B01(1);
        stage_ht(T2, 3);
        QUAD8(a0, b01, 0, 0);
        // ph6: reads a1 THEN b23 (O); stage T3,A-even; Q2'
        SBAR();
        RD_A1(1); RD_B23(1);
        stage_ht(T3, 0);
        QUAD8(a0, b23, 0, 2);
        // ph7: WAITL(0) guard; stage T3,A-odd; Q3'
        SBAR();
        WAITL(0);
        stage_ht(T3, 1);
        QUAD8(a1, b23, 4, 2);
        // ph8: stage T3,B-lo; Q4'
        SBAR();
        stage_ht(T3, 2);
        QUAD8(a1, b01, 4, 0);
    }
#undef QUAD8
#undef RD_A0
#undef RD_A1
#undef RD_B01
#undef RD_B23

    float bv[4];
#pragma unroll
    for (int nf = 0; nf < 4; ++nf)
        bv[nf] = bias[bn * 256 + wn * 64 + nf * 16 + m16];
    const int colb = bn * 256 + wn * 64 + m16;
    if (OUTBF) {
        // LDS-bounce epilogue: per-wave 16 KB scratch (disjoint slices), then
        // vectorized dwordx4 stores (128 B/row segments) instead of scalar u16.
        SBAR();   // all waves done reading sm
        u16* myl = &sm[0][0][0] + w * 8192;
#pragma unroll
        for (int mf = 0; mf < 8; ++mf)
#pragma unroll
            for (int nf = 0; nf < 4; ++nf)
#pragma unroll
                for (int r = 0; r < 4; ++r) {
                    float vv = acc[mf][nf][r] + bv[nf];
                    if (RELU) vv = fmaxf(vv, 0.f);
                    myl[(mf * 16 + quad * 4 + r) * 64 + nf * 16 + m16] = f2bf(vv);
                }
        const int grow0 = bm * 256 + wm * 128;
        const int gcol0 = bn * 256 + wn * 64 + (lane & 7) * 8;
#pragma unroll
        for (int c = 0; c < 16; ++c) {
            int row = c * 8 + (lane >> 3);
            bf16x8 v8 = *(const bf16x8*)&myl[c * 512 + lane * 8];
            *(bf16x8*)&((u16*)Cout)[(size_t)(grow0 + row) * N + gcol0] = v8;
        }
    } else {
#pragma unroll
        for (int mf = 0; mf < 8; ++mf) {
            const int row0 = bm * 256 + wm * 128 + mf * 16 + quad * 4;
#pragma unroll
            for (int nf = 0; nf < 4; ++nf) {
#pragma unroll
                for (int r = 0; r < 4; ++r) {
                    float vv = acc[mf][nf][r] + bv[nf];
                    if (RELU) vv = fmaxf(vv, 0.f);
                    ((float*)Cout)[(size_t)(row0 + r) * N + colb + nf * 16] = vv;
                }
            }
        }
    }
}

// ---------------- 128x256 split-K 4-phase GEMM (single-barrier fused) ---------
// Phase = [gate]; BARRIER; reads; stage; 16 MFMA — same rationale as gemm_8ph.
// Registers af/al/be single sets (reads same-phase-as-first-use; af consumed
// ph1,ph2 rewritten ph3; al ph1->ph3; be ph2->ph4). Stage ledger (2 insts/
// unit): ph1:T1p2 ph2:T2p0,T2p1 ph3:T2p2 ph4:T3p0,T3p1. Gates: ph1 WAITV(4)
// (bufE valid: newest 4 = T1p0,p1), ph3 last?0:4 (bufO valid). All staged
// regions' reads consumed same-phase -> complete before next barrier.
template <int RELU, int OUTBF, int SPLITK>
__global__ __launch_bounds__(512, 2) void gemm_sk(
    const u16* __restrict__ A, const u16* __restrict__ Bt,
    const float* __restrict__ bias,
    void* __restrict__ C0, void* __restrict__ C1,
    int M, int N, int K) {
    __shared__ u16 smA[2][8192];    // 128x64 per buf
    __shared__ u16 smB[2][16384];   // 256x64 per buf
    const int t = threadIdx.x;
    const int w = t >> 6, lane = t & 63;
    const int m16 = lane & 15, quad = lane >> 4;
    const int wm = w >> 2, wn = w & 3;                 // 2 x 4 wave grid
    const int nBn = N >> 8;
    const int nblk = (M >> 7) * nBn * SPLITK;
    const int o = blockIdx.x;
    const int v = (o & 7) * (nblk >> 3) + (o >> 3);    // XCD-chunked (nblk%8==0)
    const int gsz = nBn * SPLITK;
    const int bm = v / gsz;
    const int rr = v - bm * gsz;
    const int slice = rr / nBn;
    const int bn = rr - slice * nBn;
    const int Ks = K / SPLITK;
    const int nK = Ks >> 6, nIter = nK >> 1;
    const u16* Abase = A + (size_t)(bm * 128 + m16) * K + slice * Ks + quad * 8;
    const u16* Bbase = Bt + (size_t)(bn * 256 + m16) * K + slice * Ks + quad * 8;

    // unit (kt, part): part 0 = A (16 KB), 1 = B-alpha, 2 = B-beta
    auto stage_u = [&](int kt, int part) {
        if (kt < nK) {
#pragma unroll
            for (int i = 0; i < 2; ++i) {
                const int idx = i * 8 + w;
                int e;
                const u16* base;
                u16* lds;
                if (part == 0) {
                    e = idx; base = Abase; lds = &smA[kt & 1][0];
                } else {
                    const int rbs = idx >> 1;
                    const int rb = ((rbs >> 1) << 2) | (rbs & 1) | ((part == 2) ? 2 : 0);
                    e = rb * 2 + (idx & 1);
                    base = Bbase; lds = &smB[kt & 1][0];
                }
                async_copy16(&base[(size_t)((e >> 1) * 16) * K + (size_t)kt * 64 + (e & 1) * 32],
                             &lds[e * 512]);
            }
        }
    };
    auto ldsA = [&](int buf, int mf, int kc) {
        return *(const bf16x8*)&smA[buf][((wm * 4 + mf) * 2 + kc) * 512 + lane * 8];
    };
    auto ldsB = [&](int buf, int nf, int kc) {
        return *(const bf16x8*)&smB[buf][((wn * 4 + nf) * 2 + kc) * 512 + lane * 8];
    };

    f32x4 acc[4][4] = {};
    bf16x8 af[4][2], al[2][2], be[2][2];

#define RD_AF(buf)                                                              \
    _Pragma("unroll") for (int mf = 0; mf < 4; ++mf) {                          \
        af[mf][0] = ldsA(buf, mf, 0); af[mf][1] = ldsA(buf, mf, 1); }
#define RD_AL(buf)                                                              \
    _Pragma("unroll") for (int nf = 0; nf < 2; ++nf) {                          \
        al[nf][0] = ldsB(buf, nf, 0); al[nf][1] = ldsB(buf, nf, 1); }
#define RD_BE(buf)                                                              \
    _Pragma("unroll") for (int nf = 0; nf < 2; ++nf) {                          \
        be[nf][0] = ldsB(buf, 2 + nf, 0); be[nf][1] = ldsB(buf, 2 + nf, 1); }
#define QUADS(Br, NO)                                                           \
    do {                                                                        \
        __builtin_amdgcn_s_setprio(1);                                          \
        _Pragma("unroll") for (int mi = 0; mi < 4; ++mi)                        \
            _Pragma("unroll") for (int nj = 0; nj < 2; ++nj)                    \
                _Pragma("unroll") for (int kc = 0; kc < 2; ++kc)                \
                    acc[mi][(NO) + nj] =                                        \
                        MFMA16(af[mi][kc], Br[nj][kc],                          \
                               acc[mi][(NO) + nj], 0, 0, 0);                    \
        __builtin_amdgcn_s_setprio(0);                                          \
    } while (0)

    // prologue: tile0 fully + tile1 A/alpha in flight (10 insts); ph1 gates.
    stage_u(0, 0); stage_u(0, 1); stage_u(0, 2);
    stage_u(1, 0); stage_u(1, 1);

    for (int it = 0; it < nIter; ++it) {
        const int T1 = 2 * it + 1, T2 = 2 * it + 2, T3 = 2 * it + 3;
        const bool last = (it + 1 == nIter);
        // ph1: gate bufE; reads af+alpha(E); stage T1,beta; Q1
        WAITV(4);
        SBAR();
        RD_AF(0); RD_AL(0);
        stage_u(T1, 2);
        QUADS(al, 0);
        // ph2: reads beta(E); stage T2,A + T2,alpha; Q2
        SBAR();
        RD_BE(0);
        stage_u(T2, 0); stage_u(T2, 1);
        QUADS(be, 2);
        // ph3: gate bufO; reads af+alpha(O); stage T2,beta; Q1'
        if (last) { WAITV(0); } else { WAITV(4); }
        SBAR();
        RD_AF(1); RD_AL(1);
        stage_u(T2, 2);
        QUADS(al, 0);
        // ph4: reads beta(O); stage T3,A + T3,alpha; Q2'
        SBAR();
        RD_BE(1);
        stage_u(T3, 0); stage_u(T3, 1);
        QUADS(be, 2);
    }
#undef QUADS
#undef RD_AF
#undef RD_AL
#undef RD_BE

    float bv[4];
#pragma unroll
    for (int nf = 0; nf < 4; ++nf)
        bv[nf] = (SPLITK == 1 || slice == 0)
                     ? bias[bn * 256 + wn * 64 + nf * 16 + m16] : 0.f;
    void* Csel = (SPLITK > 1 && slice != 0) ? C1 : C0;
    const int colb = bn * 256 + wn * 64 + m16;
#pragma unroll
    for (int mf = 0; mf < 4; ++mf) {
        const int row0 = bm * 128 + wm * 64 + mf * 16 + quad * 4;
#pragma unroll
        for (int nf = 0; nf < 4; ++nf) {
#pragma unroll
            for (int r = 0; r < 4; ++r) {
                float vv = acc[mf][nf][r] + bv[nf];
                if (RELU) vv = fmaxf(vv, 0.f);
                size_t idx = (size_t)(row0 + r) * N + colb + nf * 16;
                if (OUTBF) ((u16*)Csel)[idx] = f2bf(vv);
                else ((float*)Csel)[idx] = vv;
            }
        }
    }
}

// ---------------- residual + layernorm (row = 1024) ----------------
// out = LN(x + x2 + res); x2 optional split-K partial. RESBF: res is bf16.
template <int RESBF>
__global__ __launch_bounds__(256) void ln_residual(
    const float* __restrict__ x, const float* x2,
    const void* __restrict__ res,
    const float* __restrict__ g, const float* __restrict__ b,
    float* out_f32, u16* __restrict__ out_bf16) {
    __shared__ float smr[8];
    int row = blockIdx.x;
    int t = threadIdx.x;
    f32x4 xv = *(const f32x4*)&x[(size_t)row * 1024 + t * 4];
    f32x4 rv;
    if (RESBF) {
        ushort4 rb = *(const ushort4*)&((const u16*)res)[(size_t)row * 1024 + t * 4];
        rv[0] = bf2f(rb.x); rv[1] = bf2f(rb.y); rv[2] = bf2f(rb.z); rv[3] = bf2f(rb.w);
    } else {
        rv = *(const f32x4*)&((const float*)res)[(size_t)row * 1024 + t * 4];
    }
    xv += rv;
    if (x2) xv += *(const f32x4*)&x2[(size_t)row * 1024 + t * 4];
    float s = xv[0] + xv[1] + xv[2] + xv[3];
    float ss = xv[0] * xv[0] + xv[1] * xv[1] + xv[2] * xv[2] + xv[3] * xv[3];
#pragma unroll
    for (int d = 1; d < 64; d <<= 1) {
        s += __shfl_xor(s, d);
        ss += __shfl_xor(ss, d);
    }
    int w = t >> 6, lane = t & 63;
    if (lane == 0) { smr[w] = s; smr[4 + w] = ss; }
    __syncthreads();
    s = smr[0] + smr[1] + smr[2] + smr[3];
    ss = smr[4] + smr[5] + smr[6] + smr[7];
    float mu = s * (1.f / 1024.f);
    float var = ss * (1.f / 1024.f) - mu * mu;
    float rs = rsqrtf(var + 1e-5f);
    f32x4 gv = *(const f32x4*)&g[t * 4];
    f32x4 bv = *(const f32x4*)&b[t * 4];
    f32x4 y;
#pragma unroll
    for (int i = 0; i < 4; ++i) y[i] = (xv[i] - mu) * rs * gv[i] + bv[i];
    if (out_f32) *(f32x4*)&out_f32[(size_t)row * 1024 + t * 4] = y;
    if (out_bf16) {
        ushort4 o;
        o.x = f2bf(y[0]); o.y = f2bf(y[1]); o.z = f2bf(y[2]); o.w = f2bf(y[3]);
        *(ushort4*)&out_bf16[(size_t)row * 1024 + t * 4] = o;
    }
}

extern "C" void kernel_launch(void* const* d_in, const int* in_sizes, int n_in,
                              void* d_out, int out_size, void* d_ws, size_t ws_size,
                              hipStream_t stream) {
    const float* q = (const float*)d_in[0];
    const float* k = (const float*)d_in[1];
    const float* v = (const float*)d_in[2];
    const int* mask = (const int*)d_in[3];
    const float* fc_b = (const float*)d_in[5];
    const float* ln1_g = (const float*)d_in[6];
    const float* ln1_b = (const float*)d_in[7];
    const float* ff_b1 = (const float*)d_in[9];
    const float* ff_b2 = (const float*)d_in[11];
    const float* ln2_g = (const float*)d_in[12];
    const float* ln2_b = (const float*)d_in[13];
    const float* fc_w = (const float*)d_in[4];
    const float* ff_w1 = (const float*)d_in[8];
    const float* ff_w2 = (const float*)d_in[10];

    char* ws = (char*)d_ws;
    const size_t MB = 1024 * 1024;
    u16* qbf = (u16*)(ws + 0);          // 8 MB (pre-scaled)
    u16* kbf = (u16*)(ws + 8 * MB);     // 8 MB
    u16* vT  = (u16*)(ws + 16 * MB);    // 8 MB
    u16* ao  = (u16*)(ws + 24 * MB);    // 8 MB
    u16* hbuf = (u16*)(ws + 0);         // 32 MB (after attention+out-proj)
    u16* fcwT = (u16*)(ws + 32 * MB);   // 2 MB
    u16* w1T  = (u16*)(ws + 34 * MB);   // 8 MB
    u16* w2T  = (u16*)(ws + 42 * MB);   // 8 MB
    float* attn_raw = (float*)(ws + 50 * MB); // 16 MB (out-proj slice 0)
    float* fc_raw   = (float*)(ws + 50 * MB); // FFN2 slice 0 (attn_raw dead)
    u16* x1bf   = (u16*)(ws + 82 * MB);       // 8 MB (LN1 out, bf16 only)
    float* attn_rawB = (float*)(ws + 0);      // 16 MB (out-proj slice 1; dead region)
    float* fcB  = (float*)(ws + 90 * MB);     // 16 MB (FFN2 slice 1)
    const bool big = ws_size >= 106 * MB;

    const float k2 = 0.03125f * 1.44269504088896340736f; // 1/sqrt(1024)*log2(e)

    // preprocessing: single fused launch (2 casts + 4 transposes)
    prep_all<<<11520, 256, 0, stream>>>(q, qbf, k2, k, kbf, v, vT,
                                        fc_w, fcwT, ff_w1, w1T, ff_w2, w2T);

    // attention
    flash_attn<<<512, 256, 0, stream>>>(qbf, kbf, vT, mask, ao);

    // out-proj: 128x256 split-K=2 4-phase fused (grid 256, 8 waves)
    gemm_sk<0, 0, 2><<<256, 512, 0, stream>>>(
        ao, fcwT, fc_b, attn_raw, attn_rawB, 4096, 1024, 1024);
    ln_residual<0><<<4096, 256, 0, stream>>>(attn_raw, attn_rawB, q, ln1_g, ln1_b,
                                             nullptr, x1bf);

    // FFN1: 256x256 8-phase fused (grid 256)
    gemm_8ph<1, 1><<<256, 512, 0, stream>>>(
        x1bf, w1T, ff_b1, hbuf, 4096, 4096, 1024);

    // FFN2: 128x256 split-K=2 4-phase fused (grid 256)
    if (big) {
        gemm_sk<0, 0, 2><<<256, 512, 0, stream>>>(
            hbuf, w2T, ff_b2, fc_raw, fcB, 4096, 1024, 4096);
        ln_residual<1><<<4096, 256, 0, stream>>>(fc_raw, fcB, x1bf, ln2_g, ln2_b,
                                                 (float*)d_out, (u16*)nullptr);
    } else {
        gemm_bt<64, 128, 0, 0, 1><<<64 * 8, 256, 0, stream>>>(
            hbuf, w2T, ff_b2, fc_raw, nullptr, 4096, 1024, 4096);
        ln_residual<1><<<4096, 256, 0, stream>>>(fc_raw, nullptr, x1bf, ln2_g, ln2_b,
                                                 (float*)d_out, (u16*)nullptr);
    }
}